// Round 1
// baseline (286.608 us; speedup 1.0000x reference)
//
#include <hip/hip_runtime.h>
#include <hip/hip_bf16.h>

// Problem constants
// obs (4096,138) f32 | obstacles (4096,5,128) f32 | act (4096,2) f32
// ow1 (22,256) ob1(256) ow2 (256,256) ob2(256)
// qw1 (396,256) qb1(256) qw2 (256,256) qb2(256) qw3 (256,1) qb3(1)
// out: (4096,) f32

typedef __attribute__((ext_vector_type(8))) short short8;
typedef __attribute__((ext_vector_type(4))) float f32x4;

#define MFMA16(A, B, C) __builtin_amdgcn_mfma_f32_16x16x32_bf16(A, B, C, 0, 0, 0)

__device__ __forceinline__ unsigned short f2b(float f) {
  __hip_bfloat16 h = __float2bfloat16(f);
  return __builtin_bit_cast(unsigned short, h);
}

// ---------------------------------------------------------------------------
// Kernel 0: pack ow1 (22x256, K-padded to 32) and ow2 (256x256) into bf16,
// laid out in MFMA-B-fragment order:
//   packed[((kblock*4 + quad)*256 + n)*8 + j] = W[kblock*32 + quad*8 + j][n]
// so a lane's 8 k-values are 16 contiguous bytes.
// ---------------------------------------------------------------------------
__global__ __launch_bounds__(256) void pack_weights(
    const float* __restrict__ ow1, const float* __restrict__ ow2,
    unsigned short* __restrict__ ow1p, unsigned short* __restrict__ ow2p) {
  int i = blockIdx.x * 256 + threadIdx.x;  // 0..65535
  if (i < 8192) {
    int j = i & 7;
    int n = (i >> 3) & 255;
    int q = i >> 11;  // 0..3
    int k = q * 8 + j;
    float v = (k < 22) ? ow1[k * 256 + n] : 0.f;
    ow1p[i] = f2b(v);
  }
  if (i < 65536) {
    int j = i & 7;
    int n = (i >> 3) & 255;
    int qq = i >> 11;  // kb*4+q, 0..31
    int q = qq & 3;
    int kb = qq >> 2;
    int k = kb * 32 + q * 8 + j;
    ow2p[i] = f2b(ow2[k * 256 + n]);
  }
}

// ---------------------------------------------------------------------------
// Kernel 1: per-batch-element obstacle MLP + masked pool.
// One block per b. 256 threads = 4 waves.
// MFMA 16x16x32 bf16 layouts (HW-verified per guide):
//   A frag: A[m = lane&15][k = (lane>>4)*8 + j], j=0..7 (16B contiguous)
//   B frag: B[k = (lane>>4)*8 + j][n = lane&15]
//   C/D:    C[row = (lane>>4)*4 + reg][col = lane&15]
// h1 in LDS uses XOR swizzle on 8-element column groups to spread banks:
//   h1[m][k] stored at m*256 + ((k>>3) ^ (m&7))*8 + (k&7)
// ---------------------------------------------------------------------------
__global__ __launch_bounds__(256, 2) void obstacle_kernel(
    const float* __restrict__ obs, const float* __restrict__ obstacles,
    const unsigned short* __restrict__ ow1p,
    const unsigned short* __restrict__ ow2p,
    const float* __restrict__ ob1, const float* __restrict__ ob2,
    float* __restrict__ pooled_out) {
  __shared__ unsigned short xs[128 * 32];   // x padded K=32, swizzle g^(n&3)
  __shared__ unsigned short h1[128 * 256];  // swizzle (k>>3)^(m&7)
  __shared__ float maskL[128];
  __shared__ float b1L[256];
  __shared__ float b2L[256];
  __shared__ float pooledL[256];
  __shared__ float vehL[24];

  const int b = blockIdx.x;
  const int tid = threadIdx.x;

  b1L[tid] = ob1[tid];
  b2L[tid] = ob2[tid];
  pooledL[tid] = 0.f;
  if (tid < 18) vehL[tid] = obs[b * 138 + tid];
  if (tid < 128) maskL[tid] = obstacles[b * 640 + 512 + tid];
  __syncthreads();

  // Build x rows: x[n][0:18]=veh, [18:22]=obstacle cols, [22:32]=0.
  if (tid < 128) {
    int n = tid;
    unsigned short row[32];
#pragma unroll
    for (int k = 0; k < 18; k++) row[k] = f2b(vehL[k]);
#pragma unroll
    for (int d = 0; d < 4; d++) row[18 + d] = f2b(obstacles[b * 640 + d * 128 + n]);
#pragma unroll
    for (int k = 22; k < 32; k++) row[k] = 0;
#pragma unroll
    for (int g = 0; g < 4; g++) {
      int gs = g ^ (n & 3);
#pragma unroll
      for (int j = 0; j < 8; j++) xs[n * 32 + gs * 8 + j] = row[g * 8 + j];
    }
  }
  __syncthreads();

  const int wave = tid >> 6;
  const int lane = tid & 63;
  const int quad = lane >> 4;
  const int l15 = lane & 15;

  // ---- Layer 1: (128x32) @ (32x256), single K-step ----
  f32x4 acc1[2][16];
  {
    short8 afr[2];
#pragma unroll
    for (int i = 0; i < 2; i++) {
      int m = (wave + i * 4) * 16 + l15;
      int gs = quad ^ (m & 3);
      afr[i] = *(const short8*)&xs[m * 32 + gs * 8];
    }
    f32x4 zero = {0.f, 0.f, 0.f, 0.f};
#pragma unroll
    for (int nt = 0; nt < 16; nt++) {
      short8 bfr = *(const short8*)&ow1p[(quad * 256 + nt * 16 + l15) * 8];
      acc1[0][nt] = MFMA16(afr[0], bfr, zero);
      acc1[1][nt] = MFMA16(afr[1], bfr, zero);
    }
  }
  // epilogue: relu(acc + b1) -> h1 bf16 (swizzled)
#pragma unroll
  for (int i = 0; i < 2; i++) {
    int mrowbase = (wave + i * 4) * 16 + quad * 4;
#pragma unroll
    for (int nt = 0; nt < 16; nt++) {
      int n = nt * 16 + l15;
      float bias = b1L[n];
      int g = n >> 3, o = n & 7;
#pragma unroll
      for (int r = 0; r < 4; r++) {
        int m = mrowbase + r;
        float v = acc1[i][nt][r] + bias;
        v = v > 0.f ? v : 0.f;
        h1[m * 256 + ((g ^ (m & 7)) << 3) + o] = f2b(v);
      }
    }
  }
  __syncthreads();

  // ---- Layer 2: (128x256) @ (256x256); wave owns M-tiles {wave, wave+4},
  //      all 16 N-tiles; B streamed from global (L1/L2-broadcast) ----
  f32x4 acc[2][16];
#pragma unroll
  for (int i = 0; i < 2; i++)
#pragma unroll
    for (int nt = 0; nt < 16; nt++) acc[i][nt] = (f32x4){0.f, 0.f, 0.f, 0.f};

#pragma unroll 1
  for (int kb = 0; kb < 8; kb++) {
    int g = kb * 4 + quad;
    int m0 = wave * 16 + l15;
    int m1 = (wave + 4) * 16 + l15;
    short8 a0 = *(const short8*)&h1[m0 * 256 + ((g ^ (m0 & 7)) << 3)];
    short8 a1 = *(const short8*)&h1[m1 * 256 + ((g ^ (m1 & 7)) << 3)];
    const unsigned short* bb = &ow2p[((kb * 4 + quad) * 256 + l15) * 8];
#pragma unroll
    for (int nt = 0; nt < 16; nt++) {
      short8 bfr = *(const short8*)&bb[nt * 128];
      acc[0][nt] = MFMA16(a0, bfr, acc[0][nt]);
      acc[1][nt] = MFMA16(a1, bfr, acc[1][nt]);
    }
  }

  // ---- Fused pool epilogue: pooled[n] = sum_m mask[m]*relu(acc+b2[n]) ----
#pragma unroll
  for (int i = 0; i < 2; i++) {
    int mbase = (wave + i * 4) * 16 + quad * 4;
#pragma unroll
    for (int nt = 0; nt < 16; nt++) {
      int n = nt * 16 + l15;
      float bias = b2L[n];
      float s = 0.f;
#pragma unroll
      for (int r = 0; r < 4; r++) {
        float v = acc[i][nt][r] + bias;
        v = v > 0.f ? v : 0.f;
        s += maskL[mbase + r] * v;
      }
      s += __shfl_xor(s, 16);  // reduce across quads (same column)
      s += __shfl_xor(s, 32);
      if (quad == 0) atomicAdd(&pooledL[n], s);
    }
  }
  __syncthreads();
  pooled_out[b * 256 + tid] = pooledL[tid];
}

// ---------------------------------------------------------------------------
// Kernel 2: head MLP, fp32 (output |q| can reach ~450; bf16 ulp there > tol).
// 512 blocks x 8 rows. comb stored transposed [k][r] so the inner loop is
// broadcast ds_read_b128 + coalesced weight load + 8 FMA.
// ---------------------------------------------------------------------------
__global__ __launch_bounds__(256) void head_mlp(
    const float* __restrict__ obs, const float* __restrict__ act,
    const float* __restrict__ pooled,
    const float* __restrict__ qw1, const float* __restrict__ qb1,
    const float* __restrict__ qw2, const float* __restrict__ qb2,
    const float* __restrict__ qw3, const float* __restrict__ qb3,
    float* __restrict__ out) {
  const int R = 8;
  __shared__ float combT[400 * R];   // [k][r]
  __shared__ float q1T[256 * 12];    // [col][r], stride 12 (16B-aligned, padded)
  __shared__ float wred[4][R];

  const int tid = threadIdx.x;
  const int r0 = blockIdx.x * R;

  // Build comb^T = [obs(138) | pooled(256) | act(2) | pad(4)=0]
  for (int r = 0; r < R; r++) {
    if (tid < 138) combT[tid * R + r] = obs[(r0 + r) * 138 + tid];
    combT[(138 + tid) * R + r] = pooled[(r0 + r) * 256 + tid];
    if (tid < 2) combT[(394 + tid) * R + r] = act[(r0 + r) * 2 + tid];
    if (tid >= 252) combT[(tid + 144) * R + r] = 0.f;  // k = 396..399
  }
  __syncthreads();

  // q1[col=tid] over 8 rows
  float a[R];
  {
    float bias = qb1[tid];
#pragma unroll
    for (int r = 0; r < R; r++) a[r] = bias;
  }
  for (int k = 0; k < 396; k++) {
    float w = qw1[k * 256 + tid];
    const f32x4* cp = (const f32x4*)&combT[k * R];
    f32x4 c0 = cp[0], c1 = cp[1];
    a[0] += c0[0] * w; a[1] += c0[1] * w; a[2] += c0[2] * w; a[3] += c0[3] * w;
    a[4] += c1[0] * w; a[5] += c1[1] * w; a[6] += c1[2] * w; a[7] += c1[3] * w;
  }
#pragma unroll
  for (int r = 0; r < R; r++) {
    a[r] = fmaxf(a[r], 0.f);
    q1T[tid * 12 + r] = a[r];
  }
  __syncthreads();

  // q2[col=tid] over 8 rows
  float a2[R];
  {
    float bias = qb2[tid];
#pragma unroll
    for (int r = 0; r < R; r++) a2[r] = bias;
  }
  for (int k = 0; k < 256; k++) {
    float w = qw2[k * 256 + tid];
    const f32x4* cp = (const f32x4*)&q1T[k * 12];
    f32x4 c0 = cp[0], c1 = cp[1];
    a2[0] += c0[0] * w; a2[1] += c0[1] * w; a2[2] += c0[2] * w; a2[3] += c0[3] * w;
    a2[4] += c1[0] * w; a2[5] += c1[1] * w; a2[6] += c1[2] * w; a2[7] += c1[3] * w;
  }
#pragma unroll
  for (int r = 0; r < R; r++) a2[r] = fmaxf(a2[r], 0.f);

  // q3: dot(q2_row, qw3) per row; cross-lane + cross-wave reduce
  const int wave = tid >> 6;
  const int lane = tid & 63;
  float w3 = qw3[tid];
#pragma unroll
  for (int r = 0; r < R; r++) {
    float s = a2[r] * w3;
    s += __shfl_xor(s, 1);
    s += __shfl_xor(s, 2);
    s += __shfl_xor(s, 4);
    s += __shfl_xor(s, 8);
    s += __shfl_xor(s, 16);
    s += __shfl_xor(s, 32);
    if (lane == 0) wred[wave][r] = s;
  }
  __syncthreads();
  if (tid < R)
    out[r0 + tid] = wred[0][tid] + wred[1][tid] + wred[2][tid] + wred[3][tid] + qb3[0];
}

// ---------------------------------------------------------------------------
extern "C" void kernel_launch(void* const* d_in, const int* in_sizes, int n_in,
                              void* d_out, int out_size, void* d_ws, size_t ws_size,
                              hipStream_t stream) {
  const float* obs       = (const float*)d_in[0];
  const float* obstacles = (const float*)d_in[1];
  const float* act       = (const float*)d_in[2];
  const float* ow1       = (const float*)d_in[3];
  const float* ob1       = (const float*)d_in[4];
  const float* ow2       = (const float*)d_in[5];
  const float* ob2       = (const float*)d_in[6];
  const float* qw1       = (const float*)d_in[7];
  const float* qb1       = (const float*)d_in[8];
  const float* qw2       = (const float*)d_in[9];
  const float* qb2       = (const float*)d_in[10];
  const float* qw3       = (const float*)d_in[11];
  const float* qb3       = (const float*)d_in[12];
  float* out = (float*)d_out;

  unsigned short* ow1p = (unsigned short*)d_ws;           // 8192 bf16
  unsigned short* ow2p = ow1p + 8192;                     // 65536 bf16
  float* pooled = (float*)(ow2p + 65536);                 // 4096*256 f32

  pack_weights<<<256, 256, 0, stream>>>(ow1, ow2, ow1p, ow2p);
  obstacle_kernel<<<4096, 256, 0, stream>>>(obs, obstacles, ow1p, ow2p, ob1, ob2,
                                            pooled);
  head_mlp<<<512, 256, 0, stream>>>(obs, act, pooled, qw1, qb1, qw2, qb2, qw3,
                                    qb3, out);
}

// Round 2
// 204.640 us; speedup vs baseline: 1.4005x; 1.4005x over previous
//
#include <hip/hip_runtime.h>
#include <hip/hip_bf16.h>

// obs (4096,138) f32 | obstacles (4096,5,128) f32 | act (4096,2) f32
// ow1 (22,256) ob1(256) ow2 (256,256) ob2(256)
// qw1 (396,256) qb1(256) qw2 (256,256) qb2(256) qw3 (256,1) qb3(1)
// out: (4096,) f32

typedef __attribute__((ext_vector_type(8))) short short8;
typedef __attribute__((ext_vector_type(4))) float f32x4;

#define MFMA16(A, B, C) __builtin_amdgcn_mfma_f32_16x16x32_bf16(A, B, C, 0, 0, 0)

__device__ __forceinline__ unsigned short f2b(float f) {
  __hip_bfloat16 h = __float2bfloat16(f);
  return __builtin_bit_cast(unsigned short, h);
}

// ---------------------------------------------------------------------------
// Kernel 0: pack weights into bf16 MFMA fragment order.
//   ow1q: A-operand layout for layer1-swapped (D = W1^T x X^T):
//     idx = mt*512 + quad*128 + l15*8 + j  ->  ow1[k=quad*8+j][n_out=mt*16+l15]
//     (k >= 22 zero-padded; K padded to 32)
//   ow2p: B-operand layout for layer2:
//     idx = ((kb*4+quad)*256 + n)*8 + j    ->  ow2[kb*32+quad*8+j][n]
// ---------------------------------------------------------------------------
__global__ __launch_bounds__(256) void pack_weights(
    const float* __restrict__ ow1, const float* __restrict__ ow2,
    unsigned short* __restrict__ ow1q, unsigned short* __restrict__ ow2p) {
  int i = blockIdx.x * 256 + threadIdx.x;  // 0..65535
  if (i < 8192) {
    int j = i & 7;
    int l15 = (i >> 3) & 15;
    int quad = (i >> 7) & 3;
    int mt = (i >> 9) & 15;
    int k = quad * 8 + j;
    int n_out = mt * 16 + l15;
    float v = (k < 22) ? ow1[k * 256 + n_out] : 0.f;
    ow1q[i] = f2b(v);
  }
  if (i < 65536) {
    int j = i & 7;
    int n = (i >> 3) & 255;
    int qq = i >> 11;  // kb*4+quad
    int q = qq & 3;
    int kb = qq >> 2;
    int k = kb * 32 + q * 8 + j;
    ow2p[i] = f2b(ow2[k * 256 + n]);
  }
}

// ---------------------------------------------------------------------------
// Kernel 1: per-batch-element obstacle MLP + masked pool. One block per b.
// 4 waves. MFMA 16x16x32 bf16 layouts:
//   A: A[m=lane&15][k=quad*8+j] | B: B[k=quad*8+j][n=lane&15]
//   C/D: row=quad*4+reg, col=lane&15
// Layer1 computed swapped (D = W1^T (256x32) x X^T (32x128)) so each lane's
// 4 C-regs are 4 consecutive k of one h1 row -> packed ds_write_b64.
// h1[m][k] swizzled: shorts addr = m*256 + (((k>>3) ^ (m&7))<<3) + (k&7).
// Layer2: wave owns ALL 8 M-tiles x 4 N-tiles (nt = wave*4..+3): B-frag
// reuse 8, ow2 read exactly once per block, B prefetched one kb ahead.
// ---------------------------------------------------------------------------
__global__ __launch_bounds__(256, 2) void obstacle_kernel(
    const float* __restrict__ obs, const float* __restrict__ obstacles,
    const unsigned short* __restrict__ ow1q,
    const unsigned short* __restrict__ ow2p,
    const float* __restrict__ ob1, const float* __restrict__ ob2,
    float* __restrict__ pooled_out) {
  __shared__ unsigned short xs[128 * 32];   // x rows, swizzle g^(n&3)
  __shared__ unsigned short h1[128 * 256];  // swizzle (k>>3)^(m&7)
  __shared__ float maskL[128];
  __shared__ float b1L[256];
  __shared__ float b2L[256];
  __shared__ float vehL[24];

  const int b = blockIdx.x;
  const int tid = threadIdx.x;

  b1L[tid] = ob1[tid];
  b2L[tid] = ob2[tid];
  if (tid < 18) vehL[tid] = obs[b * 138 + tid];
  if (tid < 128) maskL[tid] = obstacles[b * 640 + 512 + tid];
  __syncthreads();

  // Build x rows: x[n][0:18]=veh, [18:22]=obstacle cols, [22:32]=0.
  if (tid < 128) {
    int n = tid;
    unsigned short row[32];
#pragma unroll
    for (int k = 0; k < 18; k++) row[k] = f2b(vehL[k]);
#pragma unroll
    for (int d = 0; d < 4; d++) row[18 + d] = f2b(obstacles[b * 640 + d * 128 + n]);
#pragma unroll
    for (int k = 22; k < 32; k++) row[k] = 0;
#pragma unroll
    for (int g = 0; g < 4; g++) {
      int gs = g ^ (n & 3);
#pragma unroll
      for (int j = 0; j < 8; j++) xs[n * 32 + gs * 8 + j] = row[g * 8 + j];
    }
  }
  __syncthreads();

  const int wave = tid >> 6;
  const int lane = tid & 63;
  const int quad = lane >> 4;
  const int l15 = lane & 15;

  // ---- Layer 1 (swapped): wave owns mt in {wave*4..+3} (n_out tiles),
  //      all 8 nt (row tiles). Single K-step. ----
  {
    short8 wfr[4], bx[8];
#pragma unroll
    for (int i = 0; i < 4; i++) {
      int mt = wave * 4 + i;
      wfr[i] = *(const short8*)&ow1q[mt * 512 + quad * 128 + l15 * 8];
    }
#pragma unroll
    for (int nt = 0; nt < 8; nt++) {
      int n = nt * 16 + l15;
      bx[nt] = *(const short8*)&xs[n * 32 + ((quad ^ (n & 3)) << 3)];
    }
    f32x4 zero = {0.f, 0.f, 0.f, 0.f};
    f32x4 acc1[4][8];
#pragma unroll
    for (int i = 0; i < 4; i++)
#pragma unroll
      for (int nt = 0; nt < 8; nt++) acc1[i][nt] = MFMA16(wfr[i], bx[nt], zero);

    // epilogue: D[n_out][row]; lane holds n_out = mt*16+quad*4+r, row=nt*16+l15.
    // relu(v+b1) -> h1[row][n_out], 4 consecutive n_out packed -> 8B write.
#pragma unroll
    for (int i = 0; i < 4; i++) {
      int mt = wave * 4 + i;
      int nb = mt * 16 + quad * 4;  // n_out base (4 consecutive)
      float bias0 = b1L[nb + 0], bias1 = b1L[nb + 1];
      float bias2 = b1L[nb + 2], bias3 = b1L[nb + 3];
      int g = nb >> 3;            // = mt*2 + (quad>>1)
      int o = nb & 7;             // = (quad&1)*4
#pragma unroll
      for (int nt = 0; nt < 8; nt++) {
        int m = nt * 16 + l15;  // h1 row
        float v0 = fmaxf(acc1[i][nt][0] + bias0, 0.f);
        float v1 = fmaxf(acc1[i][nt][1] + bias1, 0.f);
        float v2 = fmaxf(acc1[i][nt][2] + bias2, 0.f);
        float v3 = fmaxf(acc1[i][nt][3] + bias3, 0.f);
        uint2 pk;
        pk.x = (unsigned)f2b(v0) | ((unsigned)f2b(v1) << 16);
        pk.y = (unsigned)f2b(v2) | ((unsigned)f2b(v3) << 16);
        *(uint2*)&h1[m * 256 + (((g ^ (m & 7)) << 3) + o)] = pk;
      }
    }
  }
  __syncthreads();

  // ---- Layer 2: wave owns all 8 mt, nt in {wave*4..+3}; B prefetched ----
  f32x4 acc[8][4];
#pragma unroll
  for (int mt = 0; mt < 8; mt++)
#pragma unroll
    for (int t = 0; t < 4; t++) acc[mt][t] = (f32x4){0.f, 0.f, 0.f, 0.f};

  const unsigned short* bp = &ow2p[(quad * 256 + wave * 64 + l15) * 8];
  short8 bcur[4], bnxt[4];
#pragma unroll
  for (int t = 0; t < 4; t++) bcur[t] = *(const short8*)&bp[t * 128];

#pragma unroll 1
  for (int kb = 0; kb < 8; kb++) {
    if (kb < 7) {
#pragma unroll
      for (int t = 0; t < 4; t++)
        bnxt[t] = *(const short8*)&bp[(kb + 1) * 8192 + t * 128];
    }
    short8 afr[8];
#pragma unroll
    for (int mt = 0; mt < 8; mt++) {
      int m = mt * 16 + l15;
      afr[mt] = *(const short8*)&h1[m * 256 + (((kb * 4 + quad) ^ (m & 7)) << 3)];
    }
#pragma unroll
    for (int mt = 0; mt < 8; mt++)
#pragma unroll
      for (int t = 0; t < 4; t++) acc[mt][t] = MFMA16(afr[mt], bcur[t], acc[mt][t]);
    if (kb < 7) {
#pragma unroll
      for (int t = 0; t < 4; t++) bcur[t] = bnxt[t];
    }
  }

  // ---- Pool epilogue: pooled[n] = sum_m mask[m]*relu(acc+b2[n]).
  //      Column n = nt*16+l15 owned by exactly one wave -> no atomics. ----
#pragma unroll
  for (int t = 0; t < 4; t++) {
    int n = (wave * 4 + t) * 16 + l15;
    float bias = b2L[n];
    float s = 0.f;
#pragma unroll
    for (int mt = 0; mt < 8; mt++) {
      int mb = mt * 16 + quad * 4;
#pragma unroll
      for (int r = 0; r < 4; r++) {
        float v = fmaxf(acc[mt][t][r] + bias, 0.f);
        s += maskL[mb + r] * v;
      }
    }
    s += __shfl_xor(s, 16);
    s += __shfl_xor(s, 32);
    if (quad == 0) pooled_out[b * 256 + n] = s;
  }
}

// ---------------------------------------------------------------------------
// Kernel 2: head MLP, fp32 (output magnitude too large for bf16 tolerance).
// R=4 rows/block -> 1024 blocks (4 blocks/CU, 16 waves/CU). k-loops unrolled
// x8 with batched loads: 8 outstanding global loads hide L2 latency.
// ---------------------------------------------------------------------------
__global__ __launch_bounds__(256) void head_mlp(
    const float* __restrict__ obs, const float* __restrict__ act,
    const float* __restrict__ pooled,
    const float* __restrict__ qw1, const float* __restrict__ qb1,
    const float* __restrict__ qw2, const float* __restrict__ qb2,
    const float* __restrict__ qw3, const float* __restrict__ qb3,
    float* __restrict__ out) {
  const int R = 4;
  __shared__ float combT[400 * R];  // [k][r]
  __shared__ float q1T[256 * R];    // [col][r]
  __shared__ float wred[4][R];

  const int tid = threadIdx.x;
  const int r0 = blockIdx.x * R;

  // comb^T = [obs(138) | pooled(256) | act(2) | pad(4)=0]
#pragma unroll
  for (int r = 0; r < R; r++) {
    if (tid < 138) combT[tid * R + r] = obs[(r0 + r) * 138 + tid];
    combT[(138 + tid) * R + r] = pooled[(r0 + r) * 256 + tid];
    if (tid < 2) combT[(394 + tid) * R + r] = act[(r0 + r) * 2 + tid];
    if (tid >= 252) combT[(tid + 144) * R + r] = 0.f;  // k = 396..399
  }
  __syncthreads();

  // ---- layer 1: col = tid, k = 0..395 ----
  float a[R];
  {
    float bias = qb1[tid];
#pragma unroll
    for (int r = 0; r < R; r++) a[r] = bias;
  }
  for (int k0 = 0; k0 < 392; k0 += 8) {
    float w[8];
    f32x4 c[8];
#pragma unroll
    for (int u = 0; u < 8; u++) w[u] = qw1[(k0 + u) * 256 + tid];
#pragma unroll
    for (int u = 0; u < 8; u++) c[u] = *(const f32x4*)&combT[(k0 + u) * R];
#pragma unroll
    for (int u = 0; u < 8; u++) {
      a[0] += c[u][0] * w[u]; a[1] += c[u][1] * w[u];
      a[2] += c[u][2] * w[u]; a[3] += c[u][3] * w[u];
    }
  }
#pragma unroll
  for (int u = 0; u < 4; u++) {  // tail k = 392..395
    int k = 392 + u;
    float w = qw1[k * 256 + tid];
    f32x4 c = *(const f32x4*)&combT[k * R];
    a[0] += c[0] * w; a[1] += c[1] * w; a[2] += c[2] * w; a[3] += c[3] * w;
  }
#pragma unroll
  for (int r = 0; r < R; r++) q1T[tid * R + r] = fmaxf(a[r], 0.f);
  __syncthreads();

  // ---- layer 2: col = tid, k = 0..255 ----
  float a2[R];
  {
    float bias = qb2[tid];
#pragma unroll
    for (int r = 0; r < R; r++) a2[r] = bias;
  }
  for (int k0 = 0; k0 < 256; k0 += 8) {
    float w[8];
    f32x4 c[8];
#pragma unroll
    for (int u = 0; u < 8; u++) w[u] = qw2[(k0 + u) * 256 + tid];
#pragma unroll
    for (int u = 0; u < 8; u++) c[u] = *(const f32x4*)&q1T[(k0 + u) * R];
#pragma unroll
    for (int u = 0; u < 8; u++) {
      a2[0] += c[u][0] * w[u]; a2[1] += c[u][1] * w[u];
      a2[2] += c[u][2] * w[u]; a2[3] += c[u][3] * w[u];
    }
  }
#pragma unroll
  for (int r = 0; r < R; r++) a2[r] = fmaxf(a2[r], 0.f);

  // ---- layer 3: dot(q2_row, qw3), cross-lane + cross-wave reduce ----
  const int wave = tid >> 6;
  const int lane = tid & 63;
  float w3 = qw3[tid];
#pragma unroll
  for (int r = 0; r < R; r++) {
    float s = a2[r] * w3;
    s += __shfl_xor(s, 1);
    s += __shfl_xor(s, 2);
    s += __shfl_xor(s, 4);
    s += __shfl_xor(s, 8);
    s += __shfl_xor(s, 16);
    s += __shfl_xor(s, 32);
    if (lane == 0) wred[wave][r] = s;
  }
  __syncthreads();
  if (tid < R)
    out[r0 + tid] = wred[0][tid] + wred[1][tid] + wred[2][tid] + wred[3][tid] + qb3[0];
}

// ---------------------------------------------------------------------------
extern "C" void kernel_launch(void* const* d_in, const int* in_sizes, int n_in,
                              void* d_out, int out_size, void* d_ws, size_t ws_size,
                              hipStream_t stream) {
  const float* obs       = (const float*)d_in[0];
  const float* obstacles = (const float*)d_in[1];
  const float* act       = (const float*)d_in[2];
  const float* ow1       = (const float*)d_in[3];
  const float* ob1       = (const float*)d_in[4];
  const float* ow2       = (const float*)d_in[5];
  const float* ob2       = (const float*)d_in[6];
  const float* qw1       = (const float*)d_in[7];
  const float* qb1       = (const float*)d_in[8];
  const float* qw2       = (const float*)d_in[9];
  const float* qb2       = (const float*)d_in[10];
  const float* qw3       = (const float*)d_in[11];
  const float* qb3       = (const float*)d_in[12];
  float* out = (float*)d_out;

  unsigned short* ow1q = (unsigned short*)d_ws;           // 8192 bf16
  unsigned short* ow2p = ow1q + 8192;                     // 65536 bf16
  float* pooled = (float*)(ow2p + 65536);                 // 4096*256 f32

  pack_weights<<<256, 256, 0, stream>>>(ow1, ow2, ow1q, ow2p);
  obstacle_kernel<<<4096, 256, 0, stream>>>(obs, obstacles, ow1q, ow2p, ob1, ob2,
                                            pooled);
  head_mlp<<<1024, 256, 0, stream>>>(obs, act, pooled, qw1, qb1, qw2, qb2, qw3,
                                     qb3, out);
}

// Round 4
// 181.427 us; speedup vs baseline: 1.5797x; 1.1279x over previous
//
#include <hip/hip_runtime.h>
#include <hip/hip_bf16.h>

// obs (4096,138) f32 | obstacles (4096,5,128) f32 | act (4096,2) f32
// ow1 (22,256) ob1(256) ow2 (256,256) ob2(256)
// qw1 (396,256) qb1(256) qw2 (256,256) qb2(256) qw3 (256,1) qb3(1)
// out: (4096,) f32

typedef __attribute__((ext_vector_type(8))) short short8;
typedef __attribute__((ext_vector_type(4))) float f32x4;

#define MFMA16(A, B, C) __builtin_amdgcn_mfma_f32_16x16x32_bf16(A, B, C, 0, 0, 0)

__device__ __forceinline__ unsigned short f2b(float f) {
  __hip_bfloat16 h = __float2bfloat16(f);
  return __builtin_bit_cast(unsigned short, h);
}
__device__ __forceinline__ float b2f(unsigned short u) {
  unsigned v = ((unsigned)u) << 16;
  return __builtin_bit_cast(float, v);
}
// pack two bf16 conversions into one dword (a = low half)
__device__ __forceinline__ unsigned pk2(float a, float b) {
  return (unsigned)f2b(a) | ((unsigned)f2b(b) << 16);
}

// ---------------------------------------------------------------------------
// Kernel 0: pack weights.
//  ow1q: A-frag layout for layer1-swapped obstacle MLP (K pad 32)
//  ow2p: B-frag layout, 8 kb
//  qw1h/l: B-frag layout, K pad 416 (13 kb), hi/lo bf16 split
//  qw2h/l: B-frag layout, 8 kb, hi/lo split
//  B-frag index: ((kb*4+quad)*256 + n)*8 + j  ->  W[kb*32+quad*8+j][n]
// ---------------------------------------------------------------------------
__global__ __launch_bounds__(256) void pack_weights(
    const float* __restrict__ ow1, const float* __restrict__ ow2,
    const float* __restrict__ qw1, const float* __restrict__ qw2,
    unsigned short* __restrict__ ow1q, unsigned short* __restrict__ ow2p,
    unsigned short* __restrict__ qw1h, unsigned short* __restrict__ qw1l,
    unsigned short* __restrict__ qw2h, unsigned short* __restrict__ qw2l) {
  int i = blockIdx.x * 256 + threadIdx.x;  // 0..106495
  if (i < 8192) {
    int j = i & 7;
    int l15 = (i >> 3) & 15;
    int quad = (i >> 7) & 3;
    int mt = (i >> 9) & 15;
    int k = quad * 8 + j;
    float v = (k < 22) ? ow1[k * 256 + (mt * 16 + l15)] : 0.f;
    ow1q[i] = f2b(v);
  }
  if (i < 65536) {
    int j = i & 7;
    int n = (i >> 3) & 255;
    int qq = i >> 11;
    int k = (qq >> 2) * 32 + (qq & 3) * 8 + j;
    ow2p[i] = f2b(ow2[k * 256 + n]);
    float w = qw2[k * 256 + n];
    unsigned short h = f2b(w);
    qw2h[i] = h;
    qw2l[i] = f2b(w - b2f(h));
  }
  if (i < 106496) {
    int j = i & 7;
    int n = (i >> 3) & 255;
    int qq = i >> 11;  // 0..51 = kb*4+quad
    int k = (qq >> 2) * 32 + (qq & 3) * 8 + j;
    float w = (k < 396) ? qw1[k * 256 + n] : 0.f;
    unsigned short h = f2b(w);
    qw1h[i] = h;
    qw1l[i] = f2b(w - b2f(h));
  }
}

// ---------------------------------------------------------------------------
// Kernel 1: per-batch obstacle MLP + masked pool (one block per b, 4 waves).
// MFMA 16x16x32: A[m=lane&15][k=quad*8+j] | B[k][n=lane&15] | D row=quad*4+r.
// Layer1 swapped (W1^T x X^T) so lanes own 4 consecutive h1 k -> b64 writes.
// Layer2: wave owns all 8 mt x 4 nt -> ow2 read once/block, prefetched.
// Pooled written as hi/lo bf16 pair (exact to 2^-17).
// ---------------------------------------------------------------------------
__global__ __launch_bounds__(256, 2) void obstacle_kernel(
    const float* __restrict__ obs, const float* __restrict__ obstacles,
    const unsigned short* __restrict__ ow1q,
    const unsigned short* __restrict__ ow2p,
    const float* __restrict__ ob1, const float* __restrict__ ob2,
    unsigned short* __restrict__ poolH, unsigned short* __restrict__ poolL) {
  __shared__ unsigned short xs[128 * 32];   // swizzle g^(n&3)
  __shared__ unsigned short h1[128 * 256];  // swizzle (k>>3)^(m&7)
  __shared__ float maskL[128];
  __shared__ float b1L[256];
  __shared__ float b2L[256];
  __shared__ unsigned short vehB[32];

  const int b = blockIdx.x;
  const int tid = threadIdx.x;

  b1L[tid] = ob1[tid];
  b2L[tid] = ob2[tid];
  if (tid < 18) vehB[tid] = f2b(obs[b * 138 + tid]);
  if (tid < 128) maskL[tid] = obstacles[b * 640 + 512 + tid];
  __syncthreads();

  // Build x rows: [0:18]=veh, [18:22]=obstacle cols, [22:32]=0; b128 writes.
  if (tid < 128) {
    int n = tid;
    unsigned short row[32];
#pragma unroll
    for (int k = 0; k < 18; k++) row[k] = vehB[k];
#pragma unroll
    for (int d = 0; d < 4; d++) row[18 + d] = f2b(obstacles[b * 640 + d * 128 + n]);
#pragma unroll
    for (int k = 22; k < 32; k++) row[k] = 0;
#pragma unroll
    for (int g = 0; g < 4; g++) {
      int gs = g ^ (n & 3);
      *(short8*)&xs[n * 32 + gs * 8] = *(short8*)&row[g * 8];
    }
  }
  __syncthreads();

  const int wave = tid >> 6;
  const int lane = tid & 63;
  const int quad = lane >> 4;
  const int l15 = lane & 15;

  // ---- Layer 1 (swapped): wave owns mt = wave*4..+3, all 8 row tiles ----
  {
    short8 wfr[4], bx[8];
#pragma unroll
    for (int i = 0; i < 4; i++) {
      int mt = wave * 4 + i;
      wfr[i] = *(const short8*)&ow1q[mt * 512 + quad * 128 + l15 * 8];
    }
#pragma unroll
    for (int nt = 0; nt < 8; nt++) {
      int n = nt * 16 + l15;
      bx[nt] = *(const short8*)&xs[n * 32 + ((quad ^ (n & 3)) << 3)];
    }
    f32x4 zero = {0.f, 0.f, 0.f, 0.f};
    f32x4 acc1[4][8];
#pragma unroll
    for (int i = 0; i < 4; i++)
#pragma unroll
      for (int nt = 0; nt < 8; nt++) acc1[i][nt] = MFMA16(wfr[i], bx[nt], zero);

#pragma unroll
    for (int i = 0; i < 4; i++) {
      int mt = wave * 4 + i;
      int nb = mt * 16 + quad * 4;
      float bias0 = b1L[nb + 0], bias1 = b1L[nb + 1];
      float bias2 = b1L[nb + 2], bias3 = b1L[nb + 3];
      int g = nb >> 3;
      int o = nb & 7;
#pragma unroll
      for (int nt = 0; nt < 8; nt++) {
        int m = nt * 16 + l15;
        float v0 = fmaxf(acc1[i][nt][0] + bias0, 0.f);
        float v1 = fmaxf(acc1[i][nt][1] + bias1, 0.f);
        float v2 = fmaxf(acc1[i][nt][2] + bias2, 0.f);
        float v3 = fmaxf(acc1[i][nt][3] + bias3, 0.f);
        uint2 pk;
        pk.x = pk2(v0, v1);
        pk.y = pk2(v2, v3);
        *(uint2*)&h1[m * 256 + (((g ^ (m & 7)) << 3) + o)] = pk;
      }
    }
  }
  __syncthreads();

  // ---- Layer 2: wave owns all 8 mt, nt = wave*4..+3; B prefetched ----
  f32x4 acc[8][4];
#pragma unroll
  for (int mt = 0; mt < 8; mt++)
#pragma unroll
    for (int t = 0; t < 4; t++) acc[mt][t] = (f32x4){0.f, 0.f, 0.f, 0.f};

  const unsigned short* bp = &ow2p[(quad * 256 + wave * 64 + l15) * 8];
  short8 bcur[4], bnxt[4];
#pragma unroll
  for (int t = 0; t < 4; t++) bcur[t] = *(const short8*)&bp[t * 128];

#pragma unroll 1
  for (int kb = 0; kb < 8; kb++) {
    if (kb < 7) {
#pragma unroll
      for (int t = 0; t < 4; t++)
        bnxt[t] = *(const short8*)&bp[(kb + 1) * 8192 + t * 128];
    }
    short8 afr[8];
#pragma unroll
    for (int mt = 0; mt < 8; mt++) {
      int m = mt * 16 + l15;
      afr[mt] = *(const short8*)&h1[m * 256 + (((kb * 4 + quad) ^ (m & 7)) << 3)];
    }
#pragma unroll
    for (int mt = 0; mt < 8; mt++)
#pragma unroll
      for (int t = 0; t < 4; t++) acc[mt][t] = MFMA16(afr[mt], bcur[t], acc[mt][t]);
    if (kb < 7) {
#pragma unroll
      for (int t = 0; t < 4; t++) bcur[t] = bnxt[t];
    }
  }

  // ---- Pool epilogue -> hi/lo bf16 pair ----
#pragma unroll
  for (int t = 0; t < 4; t++) {
    int n = (wave * 4 + t) * 16 + l15;
    float bias = b2L[n];
    float s = 0.f;
#pragma unroll
    for (int mt = 0; mt < 8; mt++) {
      int mb = mt * 16 + quad * 4;
#pragma unroll
      for (int r = 0; r < 4; r++) {
        float v = fmaxf(acc[mt][t][r] + bias, 0.f);
        s += maskL[mb + r] * v;
      }
    }
    s += __shfl_xor(s, 16);
    s += __shfl_xor(s, 32);
    if (quad == 0) {
      unsigned short sh = f2b(s);
      poolH[b * 256 + n] = sh;
      poolL[b * 256 + n] = f2b(s - b2f(sh));
    }
  }
}

// ---------------------------------------------------------------------------
// Kernel 2: head MLP via MFMA with hi/lo bf16 splitting (3-term product:
// Ah*Wh + Ah*Wl + Al*Wh; dropped Al*Wl ~ 2^-16 relative). 256 blocks x 512
// threads; block = 16 batch rows, wave owns 2 N-tiles. Layer 3 in f32 VALU.
// LDS row strides padded (424 / 264 shorts) to stagger banks.
// ---------------------------------------------------------------------------
__global__ __launch_bounds__(512) void head_mfma(
    const float* __restrict__ obs, const float* __restrict__ act,
    const unsigned short* __restrict__ poolH,
    const unsigned short* __restrict__ poolL,
    const unsigned short* __restrict__ qw1h,
    const unsigned short* __restrict__ qw1l,
    const unsigned short* __restrict__ qw2h,
    const unsigned short* __restrict__ qw2l,
    const float* __restrict__ qb1, const float* __restrict__ qb2,
    const float* __restrict__ qw3, const float* __restrict__ qb3,
    float* __restrict__ out) {
  const int CSTR = 424;  // comb row stride (shorts); 848B/4 %32 = 20 -> staggered
  const int HSTR = 264;  // h1 row stride; 528B/4 %32 = 4 -> staggered
  __shared__ unsigned short combH[16 * 424], combL[16 * 424];
  __shared__ unsigned short h1H[16 * 264], h1L[16 * 264];
  __shared__ float wred[8][16];

  const int tid = threadIdx.x;
  const int r0 = blockIdx.x * 16;

  // Build comb hi/lo: [obs(138) | pooled(256) | act(2) | pad->416]
  for (int idx = tid; idx < 16 * 416; idx += 512) {
    int m = idx / 416;
    int k = idx - m * 416;
    unsigned short hi, lo;
    if (k < 138) {
      float v = obs[(r0 + m) * 138 + k];
      hi = f2b(v);
      lo = f2b(v - b2f(hi));
    } else if (k < 394) {
      hi = poolH[(r0 + m) * 256 + (k - 138)];
      lo = poolL[(r0 + m) * 256 + (k - 138)];
    } else if (k < 396) {
      float v = act[(r0 + m) * 2 + (k - 394)];
      hi = f2b(v);
      lo = f2b(v - b2f(hi));
    } else {
      hi = 0; lo = 0;
    }
    combH[m * CSTR + k] = hi;
    combL[m * CSTR + k] = lo;
  }
  __syncthreads();

  const int wave = tid >> 6;
  const int lane = tid & 63;
  const int quad = lane >> 4;
  const int l15 = lane & 15;

  // ---- Layer 1: 13 kb, wave owns nt = wave*2 + {0,1} ----
  f32x4 acc[2], accm[2];
  acc[0] = acc[1] = accm[0] = accm[1] = (f32x4){0.f, 0.f, 0.f, 0.f};
#pragma unroll 1
  for (int kb = 0; kb < 13; kb++) {
    int ao = l15 * CSTR + kb * 32 + quad * 8;
    short8 ah = *(const short8*)&combH[ao];
    short8 al = *(const short8*)&combL[ao];
#pragma unroll
    for (int t = 0; t < 2; t++) {
      int n = (wave * 2 + t) * 16 + l15;
      int off = ((kb * 4 + quad) * 256 + n) * 8;
      short8 bh = *(const short8*)&qw1h[off];
      short8 bl = *(const short8*)&qw1l[off];
      acc[t] = MFMA16(ah, bh, acc[t]);
      accm[t] = MFMA16(ah, bl, accm[t]);
      accm[t] = MFMA16(al, bh, accm[t]);
    }
  }
  // epilogue -> h1 hi/lo (lane holds rows quad*4+r, col n)
#pragma unroll
  for (int t = 0; t < 2; t++) {
    int n = (wave * 2 + t) * 16 + l15;
    float bias = qb1[n];
#pragma unroll
    for (int r = 0; r < 4; r++) {
      int m = quad * 4 + r;
      float v = fmaxf(acc[t][r] + accm[t][r] + bias, 0.f);
      unsigned short hi = f2b(v);
      h1H[m * HSTR + n] = hi;
      h1L[m * HSTR + n] = f2b(v - b2f(hi));
    }
  }
  __syncthreads();

  // ---- Layer 2: 8 kb ----
  f32x4 a2[2], a2m[2];
  a2[0] = a2[1] = a2m[0] = a2m[1] = (f32x4){0.f, 0.f, 0.f, 0.f};
#pragma unroll 1
  for (int kb = 0; kb < 8; kb++) {
    int ao = l15 * HSTR + kb * 32 + quad * 8;
    short8 ah = *(const short8*)&h1H[ao];
    short8 al = *(const short8*)&h1L[ao];
#pragma unroll
    for (int t = 0; t < 2; t++) {
      int n = (wave * 2 + t) * 16 + l15;
      int off = ((kb * 4 + quad) * 256 + n) * 8;
      short8 bh = *(const short8*)&qw2h[off];
      short8 bl = *(const short8*)&qw2l[off];
      a2[t] = MFMA16(ah, bh, a2[t]);
      a2m[t] = MFMA16(ah, bl, a2m[t]);
      a2m[t] = MFMA16(al, bh, a2m[t]);
    }
  }

  // ---- Layer 3: f32 dot with qw3, reduce over n ----
#pragma unroll
  for (int r = 0; r < 4; r++) {
    float s = 0.f;
#pragma unroll
    for (int t = 0; t < 2; t++) {
      int n = (wave * 2 + t) * 16 + l15;
      float v = fmaxf(a2[t][r] + a2m[t][r] + qb2[n], 0.f);
      s += v * qw3[n];
    }
    s += __shfl_xor(s, 1);
    s += __shfl_xor(s, 2);
    s += __shfl_xor(s, 4);
    s += __shfl_xor(s, 8);
    if (l15 == 0) wred[wave][quad * 4 + r] = s;
  }
  __syncthreads();
  if (tid < 16) {
    float s = qb3[0];
#pragma unroll
    for (int w = 0; w < 8; w++) s += wred[w][tid];
    out[r0 + tid] = s;
  }
}

// ---------------------------------------------------------------------------
extern "C" void kernel_launch(void* const* d_in, const int* in_sizes, int n_in,
                              void* d_out, int out_size, void* d_ws, size_t ws_size,
                              hipStream_t stream) {
  const float* obs       = (const float*)d_in[0];
  const float* obstacles = (const float*)d_in[1];
  const float* act       = (const float*)d_in[2];
  const float* ow1       = (const float*)d_in[3];
  const float* ob1       = (const float*)d_in[4];
  const float* ow2       = (const float*)d_in[5];
  const float* ob2       = (const float*)d_in[6];
  const float* qw1       = (const float*)d_in[7];
  const float* qb1       = (const float*)d_in[8];
  const float* qw2       = (const float*)d_in[9];
  const float* qb2       = (const float*)d_in[10];
  const float* qw3       = (const float*)d_in[11];
  const float* qb3       = (const float*)d_in[12];
  float* out = (float*)d_out;

  unsigned short* ow1q = (unsigned short*)d_ws;   // 8192
  unsigned short* ow2p = ow1q + 8192;             // 65536
  unsigned short* qw1h = ow2p + 65536;            // 106496
  unsigned short* qw1l = qw1h + 106496;           // 106496
  unsigned short* qw2h = qw1l + 106496;           // 65536
  unsigned short* qw2l = qw2h + 65536;            // 65536
  unsigned short* poolH = qw2l + 65536;           // 4096*256
  unsigned short* poolL = poolH + 1048576;        // 4096*256

  pack_weights<<<416, 256, 0, stream>>>(ow1, ow2, qw1, qw2, ow1q, ow2p, qw1h,
                                        qw1l, qw2h, qw2l);
  obstacle_kernel<<<4096, 256, 0, stream>>>(obs, obstacles, ow1q, ow2p, ob1,
                                            ob2, poolH, poolL);
  head_mfma<<<256, 512, 0, stream>>>(obs, act, poolH, poolL, qw1h, qw1l, qw2h,
                                     qw2l, qb1, qb2, qw3, qb3, out);
}

// Round 5
// 180.401 us; speedup vs baseline: 1.5887x; 1.0057x over previous
//
#include <hip/hip_runtime.h>
#include <hip/hip_bf16.h>

// obs (4096,138) f32 | obstacles (4096,5,128) f32 | act (4096,2) f32
// ow1 (22,256) ob1(256) ow2 (256,256) ob2(256)
// qw1 (396,256) qb1(256) qw2 (256,256) qb2(256) qw3 (256,1) qb3(1)
// out: (4096,) f32

typedef __attribute__((ext_vector_type(8))) short short8;
typedef __attribute__((ext_vector_type(4))) float f32x4;

#define MFMA16(A, B, C) __builtin_amdgcn_mfma_f32_16x16x32_bf16(A, B, C, 0, 0, 0)

__device__ __forceinline__ unsigned short f2b(float f) {
  __hip_bfloat16 h = __float2bfloat16(f);
  return __builtin_bit_cast(unsigned short, h);
}
__device__ __forceinline__ float b2f(unsigned short u) {
  unsigned v = ((unsigned)u) << 16;
  return __builtin_bit_cast(float, v);
}
// pack two bf16 conversions into one dword (a = low half)
__device__ __forceinline__ unsigned pk2(float a, float b) {
  return (unsigned)f2b(a) | ((unsigned)f2b(b) << 16);
}

// ---------------------------------------------------------------------------
// Kernel 0: pack weights.
//  ow1q: A-frag layout for layer1-swapped obstacle MLP (K pad 32)
//  ow2p: B-frag layout, 8 kb
//  qw1h/l: B-frag layout, K pad 416 (13 kb), hi/lo bf16 split
//  qw2h/l: B-frag layout, 8 kb, hi/lo split
//  B-frag index: ((kb*4+quad)*256 + n)*8 + j  ->  W[kb*32+quad*8+j][n]
// ---------------------------------------------------------------------------
__global__ __launch_bounds__(256) void pack_weights(
    const float* __restrict__ ow1, const float* __restrict__ ow2,
    const float* __restrict__ qw1, const float* __restrict__ qw2,
    unsigned short* __restrict__ ow1q, unsigned short* __restrict__ ow2p,
    unsigned short* __restrict__ qw1h, unsigned short* __restrict__ qw1l,
    unsigned short* __restrict__ qw2h, unsigned short* __restrict__ qw2l) {
  int i = blockIdx.x * 256 + threadIdx.x;  // 0..106495
  if (i < 8192) {
    int j = i & 7;
    int l15 = (i >> 3) & 15;
    int quad = (i >> 7) & 3;
    int mt = (i >> 9) & 15;
    int k = quad * 8 + j;
    float v = (k < 22) ? ow1[k * 256 + (mt * 16 + l15)] : 0.f;
    ow1q[i] = f2b(v);
  }
  if (i < 65536) {
    int j = i & 7;
    int n = (i >> 3) & 255;
    int qq = i >> 11;
    int k = (qq >> 2) * 32 + (qq & 3) * 8 + j;
    ow2p[i] = f2b(ow2[k * 256 + n]);
    float w = qw2[k * 256 + n];
    unsigned short h = f2b(w);
    qw2h[i] = h;
    qw2l[i] = f2b(w - b2f(h));
  }
  if (i < 106496) {
    int j = i & 7;
    int n = (i >> 3) & 255;
    int qq = i >> 11;  // 0..51 = kb*4+quad
    int k = (qq >> 2) * 32 + (qq & 3) * 8 + j;
    float w = (k < 396) ? qw1[k * 256 + n] : 0.f;
    unsigned short h = f2b(w);
    qw1h[i] = h;
    qw1l[i] = f2b(w - b2f(h));
  }
}

// ---------------------------------------------------------------------------
// Kernel 1: per-batch obstacle MLP + masked pool (one block per b, 4 waves).
// MFMA 16x16x32: A[m=lane&15][k=quad*8+j] | B[k][n=lane&15] | D row=quad*4+r.
// Layer1 swapped (W1^T x X^T) so lanes own 4 consecutive h1 k -> b64 writes.
// Layer2: wave owns all 8 mt x 4 nt -> ow2 read once/block, prefetched.
// Bank-conflict fix (round 5): padded row strides instead of XOR swizzles.
//   xs stride 40 shorts (80B): bx-read slot = (5*l15+quad) mod 8 -> full spread
//   h1 stride 264 shorts (528B): write slot 4*l15+2*quad (4-way, was 64-way);
//     afr-read slot = 4*((l15+quad+4kb) mod 8) -> full spread.
// Biases read from global (L1 broadcast) to keep LDS <= 80KB -> 2 blocks/CU.
// ---------------------------------------------------------------------------
#define XSTR 40   // xs row stride in shorts
#define HSTR 264  // h1 row stride in shorts

__global__ __launch_bounds__(256, 2) void obstacle_kernel(
    const float* __restrict__ obs, const float* __restrict__ obstacles,
    const unsigned short* __restrict__ ow1q,
    const unsigned short* __restrict__ ow2p,
    const float* __restrict__ ob1, const float* __restrict__ ob2,
    unsigned short* __restrict__ poolH, unsigned short* __restrict__ poolL) {
  __shared__ unsigned short xs[128 * XSTR];  // 10240 B
  __shared__ unsigned short h1[128 * HSTR];  // 67584 B
  __shared__ float maskL[128];
  __shared__ unsigned short vehB[32];

  const int b = blockIdx.x;
  const int tid = threadIdx.x;

  if (tid < 18) vehB[tid] = f2b(obs[b * 138 + tid]);
  if (tid < 128) maskL[tid] = obstacles[b * 640 + 512 + tid];
  __syncthreads();

  // Build x rows (2 threads per row): [0:18]=veh, [18:22]=obst, [22:32]=0.
  {
    int n = tid >> 1;
    int half = tid & 1;
    if (half == 0) {
      unsigned short r01[16];
#pragma unroll
      for (int k = 0; k < 16; k++) r01[k] = vehB[k];
      *(short8*)&xs[n * XSTR + 0] = *(short8*)&r01[0];
      *(short8*)&xs[n * XSTR + 8] = *(short8*)&r01[8];
    } else {
      unsigned short r2[8];
      r2[0] = vehB[16];
      r2[1] = vehB[17];
#pragma unroll
      for (int d = 0; d < 4; d++)
        r2[2 + d] = f2b(obstacles[b * 640 + d * 128 + n]);
      r2[6] = 0; r2[7] = 0;
      *(short8*)&xs[n * XSTR + 16] = *(short8*)&r2[0];
      short8 z = {0, 0, 0, 0, 0, 0, 0, 0};
      *(short8*)&xs[n * XSTR + 24] = z;
    }
  }
  __syncthreads();

  const int wave = tid >> 6;
  const int lane = tid & 63;
  const int quad = lane >> 4;
  const int l15 = lane & 15;

  // ---- Layer 1 (swapped): wave owns mt = wave*4..+3, all 8 row tiles ----
  {
    short8 wfr[4], bx[8];
#pragma unroll
    for (int i = 0; i < 4; i++) {
      int mt = wave * 4 + i;
      wfr[i] = *(const short8*)&ow1q[mt * 512 + quad * 128 + l15 * 8];
    }
#pragma unroll
    for (int nt = 0; nt < 8; nt++) {
      int n = nt * 16 + l15;
      bx[nt] = *(const short8*)&xs[n * XSTR + quad * 8];
    }
    f32x4 zero = {0.f, 0.f, 0.f, 0.f};
    f32x4 acc1[4][8];
#pragma unroll
    for (int i = 0; i < 4; i++)
#pragma unroll
      for (int nt = 0; nt < 8; nt++) acc1[i][nt] = MFMA16(wfr[i], bx[nt], zero);

#pragma unroll
    for (int i = 0; i < 4; i++) {
      int mt = wave * 4 + i;
      int nb = mt * 16 + quad * 4;  // 4 consecutive h1 columns (k of layer2)
      float bias0 = ob1[nb + 0], bias1 = ob1[nb + 1];
      float bias2 = ob1[nb + 2], bias3 = ob1[nb + 3];
#pragma unroll
      for (int nt = 0; nt < 8; nt++) {
        int m = nt * 16 + l15;  // h1 row
        float v0 = fmaxf(acc1[i][nt][0] + bias0, 0.f);
        float v1 = fmaxf(acc1[i][nt][1] + bias1, 0.f);
        float v2 = fmaxf(acc1[i][nt][2] + bias2, 0.f);
        float v3 = fmaxf(acc1[i][nt][3] + bias3, 0.f);
        uint2 pk;
        pk.x = pk2(v0, v1);
        pk.y = pk2(v2, v3);
        *(uint2*)&h1[m * HSTR + nb] = pk;
      }
    }
  }
  __syncthreads();

  // ---- Layer 2: wave owns all 8 mt, nt = wave*4..+3; B prefetched ----
  f32x4 acc[8][4];
#pragma unroll
  for (int mt = 0; mt < 8; mt++)
#pragma unroll
    for (int t = 0; t < 4; t++) acc[mt][t] = (f32x4){0.f, 0.f, 0.f, 0.f};

  const unsigned short* bp = &ow2p[(quad * 256 + wave * 64 + l15) * 8];
  short8 bcur[4], bnxt[4];
#pragma unroll
  for (int t = 0; t < 4; t++) bcur[t] = *(const short8*)&bp[t * 128];

#pragma unroll 1
  for (int kb = 0; kb < 8; kb++) {
    if (kb < 7) {
#pragma unroll
      for (int t = 0; t < 4; t++)
        bnxt[t] = *(const short8*)&bp[(kb + 1) * 8192 + t * 128];
    }
    short8 afr[8];
#pragma unroll
    for (int mt = 0; mt < 8; mt++) {
      int m = mt * 16 + l15;
      afr[mt] = *(const short8*)&h1[m * HSTR + kb * 32 + quad * 8];
    }
#pragma unroll
    for (int mt = 0; mt < 8; mt++)
#pragma unroll
      for (int t = 0; t < 4; t++) acc[mt][t] = MFMA16(afr[mt], bcur[t], acc[mt][t]);
    if (kb < 7) {
#pragma unroll
      for (int t = 0; t < 4; t++) bcur[t] = bnxt[t];
    }
  }

  // ---- Pool epilogue -> hi/lo bf16 pair ----
#pragma unroll
  for (int t = 0; t < 4; t++) {
    int n = (wave * 4 + t) * 16 + l15;
    float bias = ob2[n];
    float s = 0.f;
#pragma unroll
    for (int mt = 0; mt < 8; mt++) {
      int mb = mt * 16 + quad * 4;
#pragma unroll
      for (int r = 0; r < 4; r++) {
        float v = fmaxf(acc[mt][t][r] + bias, 0.f);
        s += maskL[mb + r] * v;
      }
    }
    s += __shfl_xor(s, 16);
    s += __shfl_xor(s, 32);
    if (quad == 0) {
      unsigned short sh = f2b(s);
      poolH[b * 256 + n] = sh;
      poolL[b * 256 + n] = f2b(s - b2f(sh));
    }
  }
}

// ---------------------------------------------------------------------------
// Kernel 2: head MLP via MFMA with hi/lo bf16 splitting (3-term product:
// Ah*Wh + Ah*Wl + Al*Wh; dropped Al*Wl ~ 2^-16 relative). 256 blocks x 512
// threads; block = 16 batch rows, wave owns 2 N-tiles. Layer 3 in f32 VALU.
// LDS row strides padded (424 / 264 shorts) to stagger banks.
// ---------------------------------------------------------------------------
__global__ __launch_bounds__(512) void head_mfma(
    const float* __restrict__ obs, const float* __restrict__ act,
    const unsigned short* __restrict__ poolH,
    const unsigned short* __restrict__ poolL,
    const unsigned short* __restrict__ qw1h,
    const unsigned short* __restrict__ qw1l,
    const unsigned short* __restrict__ qw2h,
    const unsigned short* __restrict__ qw2l,
    const float* __restrict__ qb1, const float* __restrict__ qb2,
    const float* __restrict__ qw3, const float* __restrict__ qb3,
    float* __restrict__ out) {
  const int CSTR = 424;  // comb row stride (shorts)
  const int HSTRQ = 264; // h1 row stride (shorts)
  __shared__ unsigned short combH[16 * 424], combL[16 * 424];
  __shared__ unsigned short h1H[16 * 264], h1L[16 * 264];
  __shared__ float wred[8][16];

  const int tid = threadIdx.x;
  const int r0 = blockIdx.x * 16;

  // Build comb hi/lo: [obs(138) | pooled(256) | act(2) | pad->416]
  for (int idx = tid; idx < 16 * 416; idx += 512) {
    int m = idx / 416;
    int k = idx - m * 416;
    unsigned short hi, lo;
    if (k < 138) {
      float v = obs[(r0 + m) * 138 + k];
      hi = f2b(v);
      lo = f2b(v - b2f(hi));
    } else if (k < 394) {
      hi = poolH[(r0 + m) * 256 + (k - 138)];
      lo = poolL[(r0 + m) * 256 + (k - 138)];
    } else if (k < 396) {
      float v = act[(r0 + m) * 2 + (k - 394)];
      hi = f2b(v);
      lo = f2b(v - b2f(hi));
    } else {
      hi = 0; lo = 0;
    }
    combH[m * CSTR + k] = hi;
    combL[m * CSTR + k] = lo;
  }
  __syncthreads();

  const int wave = tid >> 6;
  const int lane = tid & 63;
  const int quad = lane >> 4;
  const int l15 = lane & 15;

  // ---- Layer 1: 13 kb, wave owns nt = wave*2 + {0,1} ----
  f32x4 acc[2], accm[2];
  acc[0] = acc[1] = accm[0] = accm[1] = (f32x4){0.f, 0.f, 0.f, 0.f};
#pragma unroll 1
  for (int kb = 0; kb < 13; kb++) {
    int ao = l15 * CSTR + kb * 32 + quad * 8;
    short8 ah = *(const short8*)&combH[ao];
    short8 al = *(const short8*)&combL[ao];
#pragma unroll
    for (int t = 0; t < 2; t++) {
      int n = (wave * 2 + t) * 16 + l15;
      int off = ((kb * 4 + quad) * 256 + n) * 8;
      short8 bh = *(const short8*)&qw1h[off];
      short8 bl = *(const short8*)&qw1l[off];
      acc[t] = MFMA16(ah, bh, acc[t]);
      accm[t] = MFMA16(ah, bl, accm[t]);
      accm[t] = MFMA16(al, bh, accm[t]);
    }
  }
  // epilogue -> h1 hi/lo (lane holds rows quad*4+r, col n)
#pragma unroll
  for (int t = 0; t < 2; t++) {
    int n = (wave * 2 + t) * 16 + l15;
    float bias = qb1[n];
#pragma unroll
    for (int r = 0; r < 4; r++) {
      int m = quad * 4 + r;
      float v = fmaxf(acc[t][r] + accm[t][r] + bias, 0.f);
      unsigned short hi = f2b(v);
      h1H[m * HSTRQ + n] = hi;
      h1L[m * HSTRQ + n] = f2b(v - b2f(hi));
    }
  }
  __syncthreads();

  // ---- Layer 2: 8 kb ----
  f32x4 a2[2], a2m[2];
  a2[0] = a2[1] = a2m[0] = a2m[1] = (f32x4){0.f, 0.f, 0.f, 0.f};
#pragma unroll 1
  for (int kb = 0; kb < 8; kb++) {
    int ao = l15 * HSTRQ + kb * 32 + quad * 8;
    short8 ah = *(const short8*)&h1H[ao];
    short8 al = *(const short8*)&h1L[ao];
#pragma unroll
    for (int t = 0; t < 2; t++) {
      int n = (wave * 2 + t) * 16 + l15;
      int off = ((kb * 4 + quad) * 256 + n) * 8;
      short8 bh = *(const short8*)&qw2h[off];
      short8 bl = *(const short8*)&qw2l[off];
      a2[t] = MFMA16(ah, bh, a2[t]);
      a2m[t] = MFMA16(ah, bl, a2m[t]);
      a2m[t] = MFMA16(al, bh, a2m[t]);
    }
  }

  // ---- Layer 3: f32 dot with qw3, reduce over n ----
#pragma unroll
  for (int r = 0; r < 4; r++) {
    float s = 0.f;
#pragma unroll
    for (int t = 0; t < 2; t++) {
      int n = (wave * 2 + t) * 16 + l15;
      float v = fmaxf(a2[t][r] + a2m[t][r] + qb2[n], 0.f);
      s += v * qw3[n];
    }
    s += __shfl_xor(s, 1);
    s += __shfl_xor(s, 2);
    s += __shfl_xor(s, 4);
    s += __shfl_xor(s, 8);
    if (l15 == 0) wred[wave][quad * 4 + r] = s;
  }
  __syncthreads();
  if (tid < 16) {
    float s = qb3[0];
#pragma unroll
    for (int w = 0; w < 8; w++) s += wred[w][tid];
    out[r0 + tid] = s;
  }
}

// ---------------------------------------------------------------------------
extern "C" void kernel_launch(void* const* d_in, const int* in_sizes, int n_in,
                              void* d_out, int out_size, void* d_ws, size_t ws_size,
                              hipStream_t stream) {
  const float* obs       = (const float*)d_in[0];
  const float* obstacles = (const float*)d_in[1];
  const float* act       = (const float*)d_in[2];
  const float* ow1       = (const float*)d_in[3];
  const float* ob1       = (const float*)d_in[4];
  const float* ow2       = (const float*)d_in[5];
  const float* ob2       = (const float*)d_in[6];
  const float* qw1       = (const float*)d_in[7];
  const float* qb1       = (const float*)d_in[8];
  const float* qw2       = (const float*)d_in[9];
  const float* qb2       = (const float*)d_in[10];
  const float* qw3       = (const float*)d_in[11];
  const float* qb3       = (const float*)d_in[12];
  float* out = (float*)d_out;

  unsigned short* ow1q = (unsigned short*)d_ws;   // 8192
  unsigned short* ow2p = ow1q + 8192;             // 65536
  unsigned short* qw1h = ow2p + 65536;            // 106496
  unsigned short* qw1l = qw1h + 106496;           // 106496
  unsigned short* qw2h = qw1l + 106496;           // 65536
  unsigned short* qw2l = qw2h + 65536;            // 65536
  unsigned short* poolH = qw2l + 65536;           // 4096*256
  unsigned short* poolL = poolH + 1048576;        // 4096*256

  pack_weights<<<416, 256, 0, stream>>>(ow1, ow2, qw1, qw2, ow1q, ow2p, qw1h,
                                        qw1l, qw2h, qw2l);
  obstacle_kernel<<<4096, 256, 0, stream>>>(obs, obstacles, ow1q, ow2p, ob1,
                                            ob2, poolH, poolL);
  head_mfma<<<256, 512, 0, stream>>>(obs, act, poolH, poolL, qw1h, qw1l, qw2h,
                                     qw2l, qb1, qb2, qw3, qb3, out);
}

// Round 6
// 176.599 us; speedup vs baseline: 1.6229x; 1.0215x over previous
//
#include <hip/hip_runtime.h>
#include <hip/hip_bf16.h>

// obs (4096,138) f32 | obstacles (4096,5,128) f32 | act (4096,2) f32
// ow1 (22,256) ob1(256) ow2 (256,256) ob2(256)
// qw1 (396,256) qb1(256) qw2 (256,256) qb2(256) qw3 (256,1) qb3(1)
// out: (4096,) f32

typedef __attribute__((ext_vector_type(8))) short short8;
typedef __attribute__((ext_vector_type(4))) float f32x4;

#define MFMA16(A, B, C) __builtin_amdgcn_mfma_f32_16x16x32_bf16(A, B, C, 0, 0, 0)

__device__ __forceinline__ unsigned short f2b(float f) {
  __hip_bfloat16 h = __float2bfloat16(f);
  return __builtin_bit_cast(unsigned short, h);
}
__device__ __forceinline__ float b2f(unsigned short u) {
  unsigned v = ((unsigned)u) << 16;
  return __builtin_bit_cast(float, v);
}
// RNE pack (slow path, used off the hot loop)
__device__ __forceinline__ unsigned pk2(float a, float b) {
  return (unsigned)f2b(a) | ((unsigned)f2b(b) << 16);
}
// fast pack: round-half-up (+0x8000) then take hi16 of both via one v_perm.
// valid for finite values; post-relu inputs are >= 0.
__device__ __forceinline__ unsigned pk2f(float a, float b) {
  unsigned ua = __builtin_bit_cast(unsigned, a) + 0x8000u;
  unsigned ub = __builtin_bit_cast(unsigned, b) + 0x8000u;
  return __builtin_amdgcn_perm(ub, ua, 0x07060302u);
}

// ---------------------------------------------------------------------------
// Kernel 0: pack weights (unchanged from round 5).
// ---------------------------------------------------------------------------
__global__ __launch_bounds__(256) void pack_weights(
    const float* __restrict__ ow1, const float* __restrict__ ow2,
    const float* __restrict__ qw1, const float* __restrict__ qw2,
    unsigned short* __restrict__ ow1q, unsigned short* __restrict__ ow2p,
    unsigned short* __restrict__ qw1h, unsigned short* __restrict__ qw1l,
    unsigned short* __restrict__ qw2h, unsigned short* __restrict__ qw2l) {
  int i = blockIdx.x * 256 + threadIdx.x;  // 0..106495
  if (i < 8192) {
    int j = i & 7;
    int l15 = (i >> 3) & 15;
    int quad = (i >> 7) & 3;
    int mt = (i >> 9) & 15;
    int k = quad * 8 + j;
    float v = (k < 22) ? ow1[k * 256 + (mt * 16 + l15)] : 0.f;
    ow1q[i] = f2b(v);
  }
  if (i < 65536) {
    int j = i & 7;
    int n = (i >> 3) & 255;
    int qq = i >> 11;
    int k = (qq >> 2) * 32 + (qq & 3) * 8 + j;
    ow2p[i] = f2b(ow2[k * 256 + n]);
    float w = qw2[k * 256 + n];
    unsigned short h = f2b(w);
    qw2h[i] = h;
    qw2l[i] = f2b(w - b2f(h));
  }
  if (i < 106496) {
    int j = i & 7;
    int n = (i >> 3) & 255;
    int qq = i >> 11;  // 0..51 = kb*4+quad
    int k = (qq >> 2) * 32 + (qq & 3) * 8 + j;
    float w = (k < 396) ? qw1[k * 256 + n] : 0.f;
    unsigned short h = f2b(w);
    qw1h[i] = h;
    qw1l[i] = f2b(w - b2f(h));
  }
}

// ---------------------------------------------------------------------------
// Kernel 1: per-batch obstacle MLP + masked pool. Round-6 rework:
//  - biases folded into MFMA C-operand init (no epilogue adds)
//  - pk2f (perm-based) bf16 packing in the h1 epilogue
//  - single-base + immediate-offset LDS addressing (offsets < 64KB)
//  - pool mask via broadcast f32x4 LDS reads
// ---------------------------------------------------------------------------
#define XSTR 40   // xs row stride in shorts
#define HSTR 264  // h1 row stride in shorts

__global__ __launch_bounds__(256, 2) void obstacle_kernel(
    const float* __restrict__ obs, const float* __restrict__ obstacles,
    const unsigned short* __restrict__ ow1q,
    const unsigned short* __restrict__ ow2p,
    const float* __restrict__ ob1, const float* __restrict__ ob2,
    unsigned short* __restrict__ poolH, unsigned short* __restrict__ poolL) {
  __shared__ unsigned short xs[128 * XSTR];  // 10240 B
  __shared__ unsigned short h1[128 * HSTR];  // 67584 B
  __shared__ float maskS[128];
  __shared__ unsigned short vehB[32];

  const int b = blockIdx.x;
  const int tid = threadIdx.x;

  if (tid < 18) vehB[tid] = f2b(obs[b * 138 + tid]);
  if (tid < 128) maskS[tid] = obstacles[b * 640 + 512 + tid];
  __syncthreads();

  // Build x rows (2 threads per row): [0:18]=veh, [18:22]=obst, [22:32]=0.
  {
    int n = tid >> 1;
    int half = tid & 1;
    unsigned short* wr = &xs[n * XSTR + half * 16];
    if (half == 0) {
      unsigned short r01[16];
#pragma unroll
      for (int k = 0; k < 16; k++) r01[k] = vehB[k];
      *(short8*)(wr + 0) = *(short8*)&r01[0];
      *(short8*)(wr + 8) = *(short8*)&r01[8];
    } else {
      unsigned short r2[8];
      r2[0] = vehB[16];
      r2[1] = vehB[17];
#pragma unroll
      for (int d = 0; d < 4; d++)
        r2[2 + d] = f2b(obstacles[b * 640 + d * 128 + n]);
      r2[6] = 0; r2[7] = 0;
      *(short8*)(wr + 0) = *(short8*)&r2[0];
      short8 z = {0, 0, 0, 0, 0, 0, 0, 0};
      *(short8*)(wr + 8) = z;
    }
  }
  __syncthreads();

  const int wave = tid >> 6;
  const int lane = tid & 63;
  const int quad = lane >> 4;
  const int l15 = lane & 15;

  // ---- Layer 1 (swapped): wave owns n_out tiles mt = wave*4..+3 ----
  {
    const unsigned short* wp = &ow1q[wave * 2048 + quad * 128 + l15 * 8];
    short8 wfr[4];
#pragma unroll
    for (int i = 0; i < 4; i++) wfr[i] = *(const short8*)(wp + i * 512);

    const unsigned short* bxp = &xs[l15 * XSTR + quad * 8];
    short8 bx[8];
#pragma unroll
    for (int nt = 0; nt < 8; nt++)
      bx[nt] = *(const short8*)(bxp + nt * 16 * XSTR);

    // bias pre-init: D rows are n_out = (wave*4+i)*16 + quad*4 + r
    const f32x4* bini = (const f32x4*)&ob1[wave * 64 + quad * 4];
    unsigned short* wr = &h1[l15 * HSTR + wave * 64 + quad * 4];

#pragma unroll
    for (int i = 0; i < 4; i++) {
      f32x4 cinit = bini[i * 4];  // ob1[wave*64 + i*16 + quad*4 ..+3]
      f32x4 acc1[8];
#pragma unroll
      for (int nt = 0; nt < 8; nt++) acc1[nt] = MFMA16(wfr[i], bx[nt], cinit);
#pragma unroll
      for (int nt = 0; nt < 8; nt++) {
        float v0 = fmaxf(acc1[nt][0], 0.f);
        float v1 = fmaxf(acc1[nt][1], 0.f);
        float v2 = fmaxf(acc1[nt][2], 0.f);
        float v3 = fmaxf(acc1[nt][3], 0.f);
        uint2 pk;
        pk.x = pk2f(v0, v1);
        pk.y = pk2f(v2, v3);
        *(uint2*)(wr + nt * 16 * HSTR + i * 16) = pk;
      }
    }
  }
  __syncthreads();

  // ---- Layer 2: wave owns all 8 mt, nt = wave*4..+3; bias in C-init ----
  f32x4 acc[8][4];
#pragma unroll
  for (int t = 0; t < 4; t++) {
    float bv = ob2[wave * 64 + t * 16 + l15];
    f32x4 bvec = {bv, bv, bv, bv};
#pragma unroll
    for (int mt = 0; mt < 8; mt++) acc[mt][t] = bvec;
  }

  const unsigned short* bp = &ow2p[(quad * 256 + wave * 64 + l15) * 8];
  const unsigned short* h1r = &h1[l15 * HSTR + quad * 8];
  short8 bcur[4], bnxt[4];
#pragma unroll
  for (int t = 0; t < 4; t++) bcur[t] = *(const short8*)(bp + t * 128);

#pragma unroll 1
  for (int kb = 0; kb < 8; kb++) {
    if (kb < 7) {
#pragma unroll
      for (int t = 0; t < 4; t++)
        bnxt[t] = *(const short8*)(bp + 8192 + t * 128);
    }
    short8 afr[8];
#pragma unroll
    for (int mt = 0; mt < 8; mt++)
      afr[mt] = *(const short8*)(h1r + mt * 16 * HSTR);
#pragma unroll
    for (int mt = 0; mt < 8; mt++)
#pragma unroll
      for (int t = 0; t < 4; t++) acc[mt][t] = MFMA16(afr[mt], bcur[t], acc[mt][t]);
    bp += 8192;
    h1r += 32;
    if (kb < 7) {
#pragma unroll
      for (int t = 0; t < 4; t++) bcur[t] = bnxt[t];
    }
  }

  // ---- Pool epilogue: pooled[n] = sum_m mask[m]*relu(h2[m][n]) ----
  f32x4 mk[8];
  const float* mkp = &maskS[quad * 4];
#pragma unroll
  for (int mt = 0; mt < 8; mt++) mk[mt] = *(const f32x4*)(mkp + mt * 16);

#pragma unroll
  for (int t = 0; t < 4; t++) {
    float s = 0.f;
#pragma unroll
    for (int mt = 0; mt < 8; mt++) {
#pragma unroll
      for (int r = 0; r < 4; r++) {
        float v = fmaxf(acc[mt][t][r], 0.f);
        s = fmaf(mk[mt][r], v, s);
      }
    }
    s += __shfl_xor(s, 16);
    s += __shfl_xor(s, 32);
    if (quad == 0) {
      int n = wave * 64 + t * 16 + l15;
      unsigned short sh = (unsigned short)(__builtin_bit_cast(unsigned, s) >> 16);
      poolH[b * 256 + n] = sh;  // truncated hi; lo captures remainder
      poolL[b * 256 + n] = f2b(s - b2f(sh));
    }
  }
}

// ---------------------------------------------------------------------------
// Kernel 2: head MLP via MFMA with hi/lo bf16 splitting (unchanged r5).
// ---------------------------------------------------------------------------
__global__ __launch_bounds__(512) void head_mfma(
    const float* __restrict__ obs, const float* __restrict__ act,
    const unsigned short* __restrict__ poolH,
    const unsigned short* __restrict__ poolL,
    const unsigned short* __restrict__ qw1h,
    const unsigned short* __restrict__ qw1l,
    const unsigned short* __restrict__ qw2h,
    const unsigned short* __restrict__ qw2l,
    const float* __restrict__ qb1, const float* __restrict__ qb2,
    const float* __restrict__ qw3, const float* __restrict__ qb3,
    float* __restrict__ out) {
  const int CSTR = 424;
  const int HSTRQ = 264;
  __shared__ unsigned short combH[16 * 424], combL[16 * 424];
  __shared__ unsigned short h1H[16 * 264], h1L[16 * 264];
  __shared__ float wred[8][16];

  const int tid = threadIdx.x;
  const int r0 = blockIdx.x * 16;

  for (int idx = tid; idx < 16 * 416; idx += 512) {
    int m = idx / 416;
    int k = idx - m * 416;
    unsigned short hi, lo;
    if (k < 138) {
      float v = obs[(r0 + m) * 138 + k];
      hi = f2b(v);
      lo = f2b(v - b2f(hi));
    } else if (k < 394) {
      hi = poolH[(r0 + m) * 256 + (k - 138)];
      lo = poolL[(r0 + m) * 256 + (k - 138)];
    } else if (k < 396) {
      float v = act[(r0 + m) * 2 + (k - 394)];
      hi = f2b(v);
      lo = f2b(v - b2f(hi));
    } else {
      hi = 0; lo = 0;
    }
    combH[m * CSTR + k] = hi;
    combL[m * CSTR + k] = lo;
  }
  __syncthreads();

  const int wave = tid >> 6;
  const int lane = tid & 63;
  const int quad = lane >> 4;
  const int l15 = lane & 15;

  f32x4 acc[2], accm[2];
  acc[0] = acc[1] = accm[0] = accm[1] = (f32x4){0.f, 0.f, 0.f, 0.f};
#pragma unroll 1
  for (int kb = 0; kb < 13; kb++) {
    int ao = l15 * CSTR + kb * 32 + quad * 8;
    short8 ah = *(const short8*)&combH[ao];
    short8 al = *(const short8*)&combL[ao];
#pragma unroll
    for (int t = 0; t < 2; t++) {
      int n = (wave * 2 + t) * 16 + l15;
      int off = ((kb * 4 + quad) * 256 + n) * 8;
      short8 bh = *(const short8*)&qw1h[off];
      short8 bl = *(const short8*)&qw1l[off];
      acc[t] = MFMA16(ah, bh, acc[t]);
      accm[t] = MFMA16(ah, bl, accm[t]);
      accm[t] = MFMA16(al, bh, accm[t]);
    }
  }
#pragma unroll
  for (int t = 0; t < 2; t++) {
    int n = (wave * 2 + t) * 16 + l15;
    float bias = qb1[n];
#pragma unroll
    for (int r = 0; r < 4; r++) {
      int m = quad * 4 + r;
      float v = fmaxf(acc[t][r] + accm[t][r] + bias, 0.f);
      unsigned short hi = f2b(v);
      h1H[m * HSTRQ + n] = hi;
      h1L[m * HSTRQ + n] = f2b(v - b2f(hi));
    }
  }
  __syncthreads();

  f32x4 a2[2], a2m[2];
  a2[0] = a2[1] = a2m[0] = a2m[1] = (f32x4){0.f, 0.f, 0.f, 0.f};
#pragma unroll 1
  for (int kb = 0; kb < 8; kb++) {
    int ao = l15 * HSTRQ + kb * 32 + quad * 8;
    short8 ah = *(const short8*)&h1H[ao];
    short8 al = *(const short8*)&h1L[ao];
#pragma unroll
    for (int t = 0; t < 2; t++) {
      int n = (wave * 2 + t) * 16 + l15;
      int off = ((kb * 4 + quad) * 256 + n) * 8;
      short8 bh = *(const short8*)&qw2h[off];
      short8 bl = *(const short8*)&qw2l[off];
      a2[t] = MFMA16(ah, bh, a2[t]);
      a2m[t] = MFMA16(ah, bl, a2m[t]);
      a2m[t] = MFMA16(al, bh, a2m[t]);
    }
  }

#pragma unroll
  for (int r = 0; r < 4; r++) {
    float s = 0.f;
#pragma unroll
    for (int t = 0; t < 2; t++) {
      int n = (wave * 2 + t) * 16 + l15;
      float v = fmaxf(a2[t][r] + a2m[t][r] + qb2[n], 0.f);
      s += v * qw3[n];
    }
    s += __shfl_xor(s, 1);
    s += __shfl_xor(s, 2);
    s += __shfl_xor(s, 4);
    s += __shfl_xor(s, 8);
    if (l15 == 0) wred[wave][quad * 4 + r] = s;
  }
  __syncthreads();
  if (tid < 16) {
    float s = qb3[0];
#pragma unroll
    for (int w = 0; w < 8; w++) s += wred[w][tid];
    out[r0 + tid] = s;
  }
}

// ---------------------------------------------------------------------------
extern "C" void kernel_launch(void* const* d_in, const int* in_sizes, int n_in,
                              void* d_out, int out_size, void* d_ws, size_t ws_size,
                              hipStream_t stream) {
  const float* obs       = (const float*)d_in[0];
  const float* obstacles = (const float*)d_in[1];
  const float* act       = (const float*)d_in[2];
  const float* ow1       = (const float*)d_in[3];
  const float* ob1       = (const float*)d_in[4];
  const float* ow2       = (const float*)d_in[5];
  const float* ob2       = (const float*)d_in[6];
  const float* qw1       = (const float*)d_in[7];
  const float* qb1       = (const float*)d_in[8];
  const float* qw2       = (const float*)d_in[9];
  const float* qb2       = (const float*)d_in[10];
  const float* qw3       = (const float*)d_in[11];
  const float* qb3       = (const float*)d_in[12];
  float* out = (float*)d_out;

  unsigned short* ow1q = (unsigned short*)d_ws;   // 8192
  unsigned short* ow2p = ow1q + 8192;             // 65536
  unsigned short* qw1h = ow2p + 65536;            // 106496
  unsigned short* qw1l = qw1h + 106496;           // 106496
  unsigned short* qw2h = qw1l + 106496;           // 65536
  unsigned short* qw2l = qw2h + 65536;            // 65536
  unsigned short* poolH = qw2l + 65536;           // 4096*256
  unsigned short* poolL = poolH + 1048576;        // 4096*256

  pack_weights<<<416, 256, 0, stream>>>(ow1, ow2, qw1, qw2, ow1q, ow2p, qw1h,
                                        qw1l, qw2h, qw2l);
  obstacle_kernel<<<4096, 256, 0, stream>>>(obs, obstacles, ow1q, ow2p, ob1,
                                            ob2, poolH, poolL);
  head_mfma<<<256, 512, 0, stream>>>(obs, act, poolH, poolL, qw1h, qw1l, qw2h,
                                     qw2l, qb1, qb2, qw3, qb3, out);
}

// Round 7
// 171.188 us; speedup vs baseline: 1.6742x; 1.0316x over previous
//
#include <hip/hip_runtime.h>
#include <hip/hip_bf16.h>

// obs (4096,138) f32 | obstacles (4096,5,128) f32 | act (4096,2) f32
// ow1 (22,256) ob1(256) ow2 (256,256) ob2(256)
// qw1 (396,256) qb1(256) qw2 (256,256) qb2(256) qw3 (256,1) qb3(1)
// out: (4096,) f32

typedef __attribute__((ext_vector_type(8))) short short8;
typedef __attribute__((ext_vector_type(4))) float f32x4;

#define MFMA16(A, B, C) __builtin_amdgcn_mfma_f32_16x16x32_bf16(A, B, C, 0, 0, 0)

__device__ __forceinline__ unsigned short f2b(float f) {
  __hip_bfloat16 h = __float2bfloat16(f);
  return __builtin_bit_cast(unsigned short, h);
}
__device__ __forceinline__ float b2f(unsigned short u) {
  unsigned v = ((unsigned)u) << 16;
  return __builtin_bit_cast(float, v);
}
// fast pack: round-half-up (+0x8000) then take hi16 of both via one v_perm.
__device__ __forceinline__ unsigned pk2f(float a, float b) {
  unsigned ua = __builtin_bit_cast(unsigned, a) + 0x8000u;
  unsigned ub = __builtin_bit_cast(unsigned, b) + 0x8000u;
  return __builtin_amdgcn_perm(ub, ua, 0x07060302u);
}

// ---------------------------------------------------------------------------
// Kernel 0: pack weights (unchanged).
// ---------------------------------------------------------------------------
__global__ __launch_bounds__(256) void pack_weights(
    const float* __restrict__ ow1, const float* __restrict__ ow2,
    const float* __restrict__ qw1, const float* __restrict__ qw2,
    unsigned short* __restrict__ ow1q, unsigned short* __restrict__ ow2p,
    unsigned short* __restrict__ qw1h, unsigned short* __restrict__ qw1l,
    unsigned short* __restrict__ qw2h, unsigned short* __restrict__ qw2l) {
  int i = blockIdx.x * 256 + threadIdx.x;  // 0..106495
  if (i < 8192) {
    int j = i & 7;
    int l15 = (i >> 3) & 15;
    int quad = (i >> 7) & 3;
    int mt = (i >> 9) & 15;
    int k = quad * 8 + j;
    float v = (k < 22) ? ow1[k * 256 + (mt * 16 + l15)] : 0.f;
    ow1q[i] = f2b(v);
  }
  if (i < 65536) {
    int j = i & 7;
    int n = (i >> 3) & 255;
    int qq = i >> 11;
    int k = (qq >> 2) * 32 + (qq & 3) * 8 + j;
    ow2p[i] = f2b(ow2[k * 256 + n]);
    float w = qw2[k * 256 + n];
    unsigned short h = f2b(w);
    qw2h[i] = h;
    qw2l[i] = f2b(w - b2f(h));
  }
  if (i < 106496) {
    int j = i & 7;
    int n = (i >> 3) & 255;
    int qq = i >> 11;  // 0..51 = kb*4+quad
    int k = (qq >> 2) * 32 + (qq & 3) * 8 + j;
    float w = (k < 396) ? qw1[k * 256 + n] : 0.f;
    unsigned short h = f2b(w);
    qw1h[i] = h;
    qw1l[i] = f2b(w - b2f(h));
  }
}

// ---------------------------------------------------------------------------
// Kernel 1 (round 7): HALF-batch-element per block — 64 obstacle rows.
// 8192 blocks x 256 threads, 4 blocks/CU (LDS 39.2KB) -> 4 waves/SIMD.
// Each block writes an f32 partial pooled row; head sums the two halves.
// ---------------------------------------------------------------------------
#define XSTR 40   // xs row stride in shorts
#define HSTR 264  // h1 row stride in shorts

__global__ __launch_bounds__(256, 4) void obstacle_kernel(
    const float* __restrict__ obs, const float* __restrict__ obstacles,
    const unsigned short* __restrict__ ow1q,
    const unsigned short* __restrict__ ow2p,
    const float* __restrict__ ob1, const float* __restrict__ ob2,
    float* __restrict__ part) {
  __shared__ unsigned short xs[64 * XSTR];  // 5120 B
  __shared__ unsigned short h1[64 * HSTR];  // 33792 B
  __shared__ float maskS[64];
  __shared__ unsigned short vehB[32];

  const int b2 = blockIdx.x;
  const int bb = b2 >> 1;         // batch element
  const int r0 = (b2 & 1) * 64;   // row offset within the 128 obstacles
  const int tid = threadIdx.x;

  if (tid < 18) vehB[tid] = f2b(obs[bb * 138 + tid]);
  if (tid < 64) maskS[tid] = obstacles[bb * 640 + 512 + r0 + tid];
  __syncthreads();

  // Build x rows (2 threads per row): [0:18]=veh, [18:22]=obst, [22:32]=0.
  if (tid < 128) {
    int n = tid >> 1;
    int half = tid & 1;
    unsigned short* wr = &xs[n * XSTR + half * 16];
    if (half == 0) {
      unsigned short r01[16];
#pragma unroll
      for (int k = 0; k < 16; k++) r01[k] = vehB[k];
      *(short8*)(wr + 0) = *(short8*)&r01[0];
      *(short8*)(wr + 8) = *(short8*)&r01[8];
    } else {
      unsigned short r2[8];
      r2[0] = vehB[16];
      r2[1] = vehB[17];
#pragma unroll
      for (int d = 0; d < 4; d++)
        r2[2 + d] = f2b(obstacles[bb * 640 + d * 128 + r0 + n]);
      r2[6] = 0; r2[7] = 0;
      *(short8*)(wr + 0) = *(short8*)&r2[0];
      short8 z = {0, 0, 0, 0, 0, 0, 0, 0};
      *(short8*)(wr + 8) = z;
    }
  }
  __syncthreads();

  const int wave = tid >> 6;
  const int lane = tid & 63;
  const int quad = lane >> 4;
  const int l15 = lane & 15;

  // ---- Layer 1 (swapped, D = W1^T x X^T): wave owns n_out tiles
  //      mt = wave*4..+3; 4 row tiles (64 rows). Bias in C-init. ----
  {
    const unsigned short* wp = &ow1q[wave * 2048 + quad * 128 + l15 * 8];
    short8 wfr[4];
#pragma unroll
    for (int i = 0; i < 4; i++) wfr[i] = *(const short8*)(wp + i * 512);

    const unsigned short* bxp = &xs[l15 * XSTR + quad * 8];
    short8 bx[4];
#pragma unroll
    for (int nt = 0; nt < 4; nt++)
      bx[nt] = *(const short8*)(bxp + nt * 16 * XSTR);

    const f32x4* bini = (const f32x4*)&ob1[wave * 64 + quad * 4];
    unsigned short* wr = &h1[l15 * HSTR + wave * 64 + quad * 4];

#pragma unroll
    for (int i = 0; i < 4; i++) {
      f32x4 cinit = bini[i * 4];
      f32x4 acc1[4];
#pragma unroll
      for (int nt = 0; nt < 4; nt++) acc1[nt] = MFMA16(wfr[i], bx[nt], cinit);
#pragma unroll
      for (int nt = 0; nt < 4; nt++) {
        float v0 = fmaxf(acc1[nt][0], 0.f);
        float v1 = fmaxf(acc1[nt][1], 0.f);
        float v2 = fmaxf(acc1[nt][2], 0.f);
        float v3 = fmaxf(acc1[nt][3], 0.f);
        uint2 pk;
        pk.x = pk2f(v0, v1);
        pk.y = pk2f(v2, v3);
        *(uint2*)(wr + nt * 16 * HSTR + i * 16) = pk;
      }
    }
  }
  __syncthreads();

  // ---- Layer 2: wave owns all 4 mt, nt = wave*4..+3; bias in C-init ----
  f32x4 acc[4][4];
#pragma unroll
  for (int t = 0; t < 4; t++) {
    float bv = ob2[wave * 64 + t * 16 + l15];
    f32x4 bvec = {bv, bv, bv, bv};
#pragma unroll
    for (int mt = 0; mt < 4; mt++) acc[mt][t] = bvec;
  }

  const unsigned short* bp = &ow2p[(quad * 256 + wave * 64 + l15) * 8];
  const unsigned short* h1r = &h1[l15 * HSTR + quad * 8];
  short8 bcur[4], bnxt[4];
#pragma unroll
  for (int t = 0; t < 4; t++) bcur[t] = *(const short8*)(bp + t * 128);

#pragma unroll 1
  for (int kb = 0; kb < 8; kb++) {
    if (kb < 7) {
#pragma unroll
      for (int t = 0; t < 4; t++)
        bnxt[t] = *(const short8*)(bp + 8192 + t * 128);
    }
    short8 afr[4];
#pragma unroll
    for (int mt = 0; mt < 4; mt++)
      afr[mt] = *(const short8*)(h1r + mt * 16 * HSTR);
#pragma unroll
    for (int mt = 0; mt < 4; mt++)
#pragma unroll
      for (int t = 0; t < 4; t++) acc[mt][t] = MFMA16(afr[mt], bcur[t], acc[mt][t]);
    bp += 8192;
    h1r += 32;
    if (kb < 7) {
#pragma unroll
      for (int t = 0; t < 4; t++) bcur[t] = bnxt[t];
    }
  }

  // ---- Pool epilogue: partial[n] = sum_{m in half} mask[m]*relu(h2) ----
  f32x4 mk[4];
  const float* mkp = &maskS[quad * 4];
#pragma unroll
  for (int mt = 0; mt < 4; mt++) mk[mt] = *(const f32x4*)(mkp + mt * 16);

#pragma unroll
  for (int t = 0; t < 4; t++) {
    float s = 0.f;
#pragma unroll
    for (int mt = 0; mt < 4; mt++) {
#pragma unroll
      for (int r = 0; r < 4; r++) {
        float v = fmaxf(acc[mt][t][r], 0.f);
        s = fmaf(mk[mt][r], v, s);
      }
    }
    s += __shfl_xor(s, 16);
    s += __shfl_xor(s, 32);
    if (quad == 0) part[b2 * 256 + wave * 64 + t * 16 + l15] = s;
  }
}

// ---------------------------------------------------------------------------
// Kernel 2: head MLP via MFMA, hi/lo bf16 split. Round 7: 1024 threads
// (16 waves, wave owns 1 N-tile) -> 4 waves/SIMD. Sums the two pool
// partials during the comb build.
// ---------------------------------------------------------------------------
__global__ __launch_bounds__(1024) void head_mfma(
    const float* __restrict__ obs, const float* __restrict__ act,
    const float* __restrict__ part,
    const unsigned short* __restrict__ qw1h,
    const unsigned short* __restrict__ qw1l,
    const unsigned short* __restrict__ qw2h,
    const unsigned short* __restrict__ qw2l,
    const float* __restrict__ qb1, const float* __restrict__ qb2,
    const float* __restrict__ qw3, const float* __restrict__ qb3,
    float* __restrict__ out) {
  const int CSTR = 424;
  const int HSTRQ = 264;
  __shared__ unsigned short combH[16 * 424], combL[16 * 424];
  __shared__ unsigned short h1H[16 * 264], h1L[16 * 264];
  __shared__ float wred[16][16];

  const int tid = threadIdx.x;
  const int r0 = blockIdx.x * 16;

  // Build comb hi/lo: [obs(138) | pooled(256)=part0+part1 | act(2) | pad->416]
  for (int idx = tid; idx < 16 * 416; idx += 1024) {
    int m = idx / 416;
    int k = idx - m * 416;
    unsigned short hi, lo;
    if (k < 138) {
      float v = obs[(r0 + m) * 138 + k];
      hi = f2b(v);
      lo = f2b(v - b2f(hi));
    } else if (k < 394) {
      int g = (r0 + m) * 2;
      float v = part[g * 256 + (k - 138)] + part[(g + 1) * 256 + (k - 138)];
      hi = f2b(v);
      lo = f2b(v - b2f(hi));
    } else if (k < 396) {
      float v = act[(r0 + m) * 2 + (k - 394)];
      hi = f2b(v);
      lo = f2b(v - b2f(hi));
    } else {
      hi = 0; lo = 0;
    }
    combH[m * CSTR + k] = hi;
    combL[m * CSTR + k] = lo;
  }
  __syncthreads();

  const int wave = tid >> 6;  // 0..15 = N-tile
  const int lane = tid & 63;
  const int quad = lane >> 4;
  const int l15 = lane & 15;
  const int n = wave * 16 + l15;

  // ---- Layer 1: 13 kb ----
  f32x4 acc = {0.f, 0.f, 0.f, 0.f}, accm = {0.f, 0.f, 0.f, 0.f};
#pragma unroll 1
  for (int kb = 0; kb < 13; kb++) {
    int ao = l15 * CSTR + kb * 32 + quad * 8;
    short8 ah = *(const short8*)&combH[ao];
    short8 al = *(const short8*)&combL[ao];
    int off = ((kb * 4 + quad) * 256 + n) * 8;
    short8 bh = *(const short8*)&qw1h[off];
    short8 bl = *(const short8*)&qw1l[off];
    acc = MFMA16(ah, bh, acc);
    accm = MFMA16(ah, bl, accm);
    accm = MFMA16(al, bh, accm);
  }
  {
    float bias = qb1[n];
#pragma unroll
    for (int r = 0; r < 4; r++) {
      int m = quad * 4 + r;
      float v = fmaxf(acc[r] + accm[r] + bias, 0.f);
      unsigned short hi = f2b(v);
      h1H[m * HSTRQ + n] = hi;
      h1L[m * HSTRQ + n] = f2b(v - b2f(hi));
    }
  }
  __syncthreads();

  // ---- Layer 2: 8 kb ----
  f32x4 a2 = {0.f, 0.f, 0.f, 0.f}, a2m = {0.f, 0.f, 0.f, 0.f};
#pragma unroll 1
  for (int kb = 0; kb < 8; kb++) {
    int ao = l15 * HSTRQ + kb * 32 + quad * 8;
    short8 ah = *(const short8*)&h1H[ao];
    short8 al = *(const short8*)&h1L[ao];
    int off = ((kb * 4 + quad) * 256 + n) * 8;
    short8 bh = *(const short8*)&qw2h[off];
    short8 bl = *(const short8*)&qw2l[off];
    a2 = MFMA16(ah, bh, a2);
    a2m = MFMA16(ah, bl, a2m);
    a2m = MFMA16(al, bh, a2m);
  }

  // ---- Layer 3: f32 dot with qw3, reduce over the wave's 16 cols ----
  {
    float w3 = qw3[n];
    float qb2n = qb2[n];
#pragma unroll
    for (int r = 0; r < 4; r++) {
      float v = fmaxf(a2[r] + a2m[r] + qb2n, 0.f);
      float s = v * w3;
      s += __shfl_xor(s, 1);
      s += __shfl_xor(s, 2);
      s += __shfl_xor(s, 4);
      s += __shfl_xor(s, 8);
      if (l15 == 0) wred[wave][quad * 4 + r] = s;
    }
  }
  __syncthreads();
  if (tid < 16) {
    float s = qb3[0];
#pragma unroll
    for (int w = 0; w < 16; w++) s += wred[w][tid];
    out[r0 + tid] = s;
  }
}

// ---------------------------------------------------------------------------
extern "C" void kernel_launch(void* const* d_in, const int* in_sizes, int n_in,
                              void* d_out, int out_size, void* d_ws, size_t ws_size,
                              hipStream_t stream) {
  const float* obs       = (const float*)d_in[0];
  const float* obstacles = (const float*)d_in[1];
  const float* act       = (const float*)d_in[2];
  const float* ow1       = (const float*)d_in[3];
  const float* ob1       = (const float*)d_in[4];
  const float* ow2       = (const float*)d_in[5];
  const float* ob2       = (const float*)d_in[6];
  const float* qw1       = (const float*)d_in[7];
  const float* qb1       = (const float*)d_in[8];
  const float* qw2       = (const float*)d_in[9];
  const float* qb2       = (const float*)d_in[10];
  const float* qw3       = (const float*)d_in[11];
  const float* qb3       = (const float*)d_in[12];
  float* out = (float*)d_out;

  unsigned short* ow1q = (unsigned short*)d_ws;   // 8192
  unsigned short* ow2p = ow1q + 8192;             // 65536
  unsigned short* qw1h = ow2p + 65536;            // 106496
  unsigned short* qw1l = qw1h + 106496;           // 106496
  unsigned short* qw2h = qw1l + 106496;           // 65536
  unsigned short* qw2l = qw2h + 65536;            // 65536
  float* part = (float*)(qw2l + 65536);           // 8192*256 f32 (8 MB)

  pack_weights<<<416, 256, 0, stream>>>(ow1, ow2, qw1, qw2, ow1q, ow2p, qw1h,
                                        qw1l, qw2h, qw2l);
  obstacle_kernel<<<8192, 256, 0, stream>>>(obs, obstacles, ow1q, ow2p, ob1,
                                            ob2, part);
  head_mfma<<<256, 1024, 0, stream>>>(obs, act, part, qw1h, qw1l, qw2h,
                                      qw2l, qb1, qb2, qw3, qb3, out);
}

// Round 8
// 166.551 us; speedup vs baseline: 1.7208x; 1.0278x over previous
//
#include <hip/hip_runtime.h>
#include <hip/hip_bf16.h>

// obs (4096,138) f32 | obstacles (4096,5,128) f32 | act (4096,2) f32
// ow1 (22,256) ob1(256) ow2 (256,256) ob2(256)
// qw1 (396,256) qb1(256) qw2 (256,256) qb2(256) qw3 (256,1) qb3(1)
// out: (4096,) f32

typedef __attribute__((ext_vector_type(8))) short short8;
typedef __attribute__((ext_vector_type(4))) float f32x4;

#define MFMA16(A, B, C) __builtin_amdgcn_mfma_f32_16x16x32_bf16(A, B, C, 0, 0, 0)

__device__ __forceinline__ unsigned short f2b(float f) {
  __hip_bfloat16 h = __float2bfloat16(f);
  return __builtin_bit_cast(unsigned short, h);
}
__device__ __forceinline__ float b2f(unsigned short u) {
  unsigned v = ((unsigned)u) << 16;
  return __builtin_bit_cast(float, v);
}
// fast pack: round-half-up (+0x8000) then take hi16 of both via one v_perm.
__device__ __forceinline__ unsigned pk2f(float a, float b) {
  unsigned ua = __builtin_bit_cast(unsigned, a) + 0x8000u;
  unsigned ub = __builtin_bit_cast(unsigned, b) + 0x8000u;
  return __builtin_amdgcn_perm(ub, ua, 0x07060302u);
}

// ---------------------------------------------------------------------------
// Kernel 0: pack weights (unchanged).
// ---------------------------------------------------------------------------
__global__ __launch_bounds__(256) void pack_weights(
    const float* __restrict__ ow1, const float* __restrict__ ow2,
    const float* __restrict__ qw1, const float* __restrict__ qw2,
    unsigned short* __restrict__ ow1q, unsigned short* __restrict__ ow2p,
    unsigned short* __restrict__ qw1h, unsigned short* __restrict__ qw1l,
    unsigned short* __restrict__ qw2h, unsigned short* __restrict__ qw2l) {
  int i = blockIdx.x * 256 + threadIdx.x;  // 0..106495
  if (i < 8192) {
    int j = i & 7;
    int l15 = (i >> 3) & 15;
    int quad = (i >> 7) & 3;
    int mt = (i >> 9) & 15;
    int k = quad * 8 + j;
    float v = (k < 22) ? ow1[k * 256 + (mt * 16 + l15)] : 0.f;
    ow1q[i] = f2b(v);
  }
  if (i < 65536) {
    int j = i & 7;
    int n = (i >> 3) & 255;
    int qq = i >> 11;
    int k = (qq >> 2) * 32 + (qq & 3) * 8 + j;
    ow2p[i] = f2b(ow2[k * 256 + n]);
    float w = qw2[k * 256 + n];
    unsigned short h = f2b(w);
    qw2h[i] = h;
    qw2l[i] = f2b(w - b2f(h));
  }
  if (i < 106496) {
    int j = i & 7;
    int n = (i >> 3) & 255;
    int qq = i >> 11;  // 0..51 = kb*4+quad
    int k = (qq >> 2) * 32 + (qq & 3) * 8 + j;
    float w = (k < 396) ? qw1[k * 256 + n] : 0.f;
    unsigned short h = f2b(w);
    qw1h[i] = h;
    qw1l[i] = f2b(w - b2f(h));
  }
}

// ---------------------------------------------------------------------------
// Kernel 1 (round 8): full 128-row batch element per block, 512 threads
// (8 waves), 2 blocks/CU (LDS 78.4KB) -> 4 waves/SIMD.
// Layer-2 wave tiling: 8 M-tiles x 2 N-tiles -> B-frag reuse 8, ow2p read
// exactly once per block (512MB total vs 1GB in round 7).
// ---------------------------------------------------------------------------
#define XSTR 40   // xs row stride in shorts
#define HSTR 264  // h1 row stride in shorts

__global__ __launch_bounds__(512, 4) void obstacle_kernel(
    const float* __restrict__ obs, const float* __restrict__ obstacles,
    const unsigned short* __restrict__ ow1q,
    const unsigned short* __restrict__ ow2p,
    const float* __restrict__ ob1, const float* __restrict__ ob2,
    unsigned short* __restrict__ poolH, unsigned short* __restrict__ poolL) {
  __shared__ unsigned short xs[128 * XSTR];  // 10240 B
  __shared__ unsigned short h1[128 * HSTR];  // 67584 B
  __shared__ float maskS[128];
  __shared__ unsigned short vehB[32];

  const int b = blockIdx.x;
  const int tid = threadIdx.x;

  if (tid < 18) vehB[tid] = f2b(obs[b * 138 + tid]);
  if (tid < 128) maskS[tid] = obstacles[b * 640 + 512 + tid];
  __syncthreads();

  // Build x rows (2 threads per row, tid<256): [0:18]=veh, [18:22]=obst.
  if (tid < 256) {
    int n = tid >> 1;
    int half = tid & 1;
    unsigned short* wr = &xs[n * XSTR + half * 16];
    if (half == 0) {
      unsigned short r01[16];
#pragma unroll
      for (int k = 0; k < 16; k++) r01[k] = vehB[k];
      *(short8*)(wr + 0) = *(short8*)&r01[0];
      *(short8*)(wr + 8) = *(short8*)&r01[8];
    } else {
      unsigned short r2[8];
      r2[0] = vehB[16];
      r2[1] = vehB[17];
#pragma unroll
      for (int d = 0; d < 4; d++)
        r2[2 + d] = f2b(obstacles[b * 640 + d * 128 + n]);
      r2[6] = 0; r2[7] = 0;
      *(short8*)(wr + 0) = *(short8*)&r2[0];
      short8 z = {0, 0, 0, 0, 0, 0, 0, 0};
      *(short8*)(wr + 8) = z;
    }
  }
  __syncthreads();

  const int wave = tid >> 6;   // 0..7
  const int lane = tid & 63;
  const int quad = lane >> 4;
  const int l15 = lane & 15;

  // ---- Layer 1 (swapped, D = W1^T x X^T): wave owns 2 n_out tiles
  //      (wave*2, wave*2+1), all 8 row tiles. Bias in C-init. ----
  {
    const unsigned short* wp = &ow1q[wave * 1024 + quad * 128 + l15 * 8];
    short8 wfr[2];
#pragma unroll
    for (int i = 0; i < 2; i++) wfr[i] = *(const short8*)(wp + i * 512);

    const unsigned short* bxp = &xs[l15 * XSTR + quad * 8];
    short8 bx[8];
#pragma unroll
    for (int nt = 0; nt < 8; nt++)
      bx[nt] = *(const short8*)(bxp + nt * 16 * XSTR);

    unsigned short* wrb = &h1[l15 * HSTR + wave * 32 + quad * 4];

#pragma unroll
    for (int i = 0; i < 2; i++) {
      f32x4 cinit = *(const f32x4*)&ob1[wave * 32 + i * 16 + quad * 4];
      f32x4 acc1[8];
#pragma unroll
      for (int nt = 0; nt < 8; nt++) acc1[nt] = MFMA16(wfr[i], bx[nt], cinit);
#pragma unroll
      for (int nt = 0; nt < 8; nt++) {
        float v0 = fmaxf(acc1[nt][0], 0.f);
        float v1 = fmaxf(acc1[nt][1], 0.f);
        float v2 = fmaxf(acc1[nt][2], 0.f);
        float v3 = fmaxf(acc1[nt][3], 0.f);
        uint2 pk;
        pk.x = pk2f(v0, v1);
        pk.y = pk2f(v2, v3);
        *(uint2*)(wrb + nt * 16 * HSTR + i * 16) = pk;
      }
    }
  }
  __syncthreads();

  // ---- Layer 2: wave owns ALL 8 mt, nt = wave*2..+1 (B reuse 8);
  //      bias in C-init; B prefetched one kb ahead. ----
  f32x4 acc[8][2];
#pragma unroll
  for (int t = 0; t < 2; t++) {
    float bv = ob2[wave * 32 + t * 16 + l15];
    f32x4 bvec = {bv, bv, bv, bv};
#pragma unroll
    for (int mt = 0; mt < 8; mt++) acc[mt][t] = bvec;
  }

  const unsigned short* bp = &ow2p[(quad * 256 + wave * 32 + l15) * 8];
  const unsigned short* h1r = &h1[l15 * HSTR + quad * 8];
  short8 bcur[2], bnxt[2];
#pragma unroll
  for (int t = 0; t < 2; t++) bcur[t] = *(const short8*)(bp + t * 128);

#pragma unroll 1
  for (int kb = 0; kb < 8; kb++) {
    if (kb < 7) {
#pragma unroll
      for (int t = 0; t < 2; t++)
        bnxt[t] = *(const short8*)(bp + 8192 + t * 128);
    }
    short8 afr[8];
#pragma unroll
    for (int mt = 0; mt < 8; mt++)
      afr[mt] = *(const short8*)(h1r + mt * 16 * HSTR);
#pragma unroll
    for (int mt = 0; mt < 8; mt++)
#pragma unroll
      for (int t = 0; t < 2; t++) acc[mt][t] = MFMA16(afr[mt], bcur[t], acc[mt][t]);
    bp += 8192;
    h1r += 32;
    if (kb < 7) {
#pragma unroll
      for (int t = 0; t < 2; t++) bcur[t] = bnxt[t];
    }
  }

  // ---- Pool epilogue: pooled[n] = sum_m mask[m]*relu(h2[m][n]);
  //      column n owned by exactly one wave. ----
  f32x4 mk[8];
  const float* mkp = &maskS[quad * 4];
#pragma unroll
  for (int mt = 0; mt < 8; mt++) mk[mt] = *(const f32x4*)(mkp + mt * 16);

#pragma unroll
  for (int t = 0; t < 2; t++) {
    float s = 0.f;
#pragma unroll
    for (int mt = 0; mt < 8; mt++) {
#pragma unroll
      for (int r = 0; r < 4; r++) {
        float v = fmaxf(acc[mt][t][r], 0.f);
        s = fmaf(mk[mt][r], v, s);
      }
    }
    s += __shfl_xor(s, 16);
    s += __shfl_xor(s, 32);
    if (quad == 0) {
      int n = wave * 32 + t * 16 + l15;
      unsigned short sh = (unsigned short)(__builtin_bit_cast(unsigned, s) >> 16);
      poolH[b * 256 + n] = sh;  // truncated hi; lo captures remainder
      poolL[b * 256 + n] = f2b(s - b2f(sh));
    }
  }
}

// ---------------------------------------------------------------------------
// Kernel 2: head MLP via MFMA, hi/lo bf16 split (3-term). 256 blocks x 1024
// threads (16 waves, wave owns 1 N-tile). Layer 3 f32 VALU.
// ---------------------------------------------------------------------------
__global__ __launch_bounds__(1024) void head_mfma(
    const float* __restrict__ obs, const float* __restrict__ act,
    const unsigned short* __restrict__ poolH,
    const unsigned short* __restrict__ poolL,
    const unsigned short* __restrict__ qw1h,
    const unsigned short* __restrict__ qw1l,
    const unsigned short* __restrict__ qw2h,
    const unsigned short* __restrict__ qw2l,
    const float* __restrict__ qb1, const float* __restrict__ qb2,
    const float* __restrict__ qw3, const float* __restrict__ qb3,
    float* __restrict__ out) {
  const int CSTR = 424;
  const int HSTRQ = 264;
  __shared__ unsigned short combH[16 * 424], combL[16 * 424];
  __shared__ unsigned short h1H[16 * 264], h1L[16 * 264];
  __shared__ float wred[16][16];

  const int tid = threadIdx.x;
  const int r0 = blockIdx.x * 16;

  // Build comb hi/lo: [obs(138) | pooled(256) | act(2) | pad->416]
  for (int idx = tid; idx < 16 * 416; idx += 1024) {
    int m = idx / 416;
    int k = idx - m * 416;
    unsigned short hi, lo;
    if (k < 138) {
      float v = obs[(r0 + m) * 138 + k];
      hi = f2b(v);
      lo = f2b(v - b2f(hi));
    } else if (k < 394) {
      hi = poolH[(r0 + m) * 256 + (k - 138)];
      lo = poolL[(r0 + m) * 256 + (k - 138)];
    } else if (k < 396) {
      float v = act[(r0 + m) * 2 + (k - 394)];
      hi = f2b(v);
      lo = f2b(v - b2f(hi));
    } else {
      hi = 0; lo = 0;
    }
    combH[m * CSTR + k] = hi;
    combL[m * CSTR + k] = lo;
  }
  __syncthreads();

  const int wave = tid >> 6;  // 0..15 = N-tile
  const int lane = tid & 63;
  const int quad = lane >> 4;
  const int l15 = lane & 15;
  const int n = wave * 16 + l15;

  // ---- Layer 1: 13 kb ----
  f32x4 acc = {0.f, 0.f, 0.f, 0.f}, accm = {0.f, 0.f, 0.f, 0.f};
#pragma unroll 1
  for (int kb = 0; kb < 13; kb++) {
    int ao = l15 * CSTR + kb * 32 + quad * 8;
    short8 ah = *(const short8*)&combH[ao];
    short8 al = *(const short8*)&combL[ao];
    int off = ((kb * 4 + quad) * 256 + n) * 8;
    short8 bh = *(const short8*)&qw1h[off];
    short8 bl = *(const short8*)&qw1l[off];
    acc = MFMA16(ah, bh, acc);
    accm = MFMA16(ah, bl, accm);
    accm = MFMA16(al, bh, accm);
  }
  {
    float bias = qb1[n];
#pragma unroll
    for (int r = 0; r < 4; r++) {
      int m = quad * 4 + r;
      float v = fmaxf(acc[r] + accm[r] + bias, 0.f);
      unsigned short hi = f2b(v);
      h1H[m * HSTRQ + n] = hi;
      h1L[m * HSTRQ + n] = f2b(v - b2f(hi));
    }
  }
  __syncthreads();

  // ---- Layer 2: 8 kb ----
  f32x4 a2 = {0.f, 0.f, 0.f, 0.f}, a2m = {0.f, 0.f, 0.f, 0.f};
#pragma unroll 1
  for (int kb = 0; kb < 8; kb++) {
    int ao = l15 * HSTRQ + kb * 32 + quad * 8;
    short8 ah = *(const short8*)&h1H[ao];
    short8 al = *(const short8*)&h1L[ao];
    int off = ((kb * 4 + quad) * 256 + n) * 8;
    short8 bh = *(const short8*)&qw2h[off];
    short8 bl = *(const short8*)&qw2l[off];
    a2 = MFMA16(ah, bh, a2);
    a2m = MFMA16(ah, bl, a2m);
    a2m = MFMA16(al, bh, a2m);
  }

  // ---- Layer 3: f32 dot with qw3, reduce over the wave's 16 cols ----
  {
    float w3 = qw3[n];
    float qb2n = qb2[n];
#pragma unroll
    for (int r = 0; r < 4; r++) {
      float v = fmaxf(a2[r] + a2m[r] + qb2n, 0.f);
      float s = v * w3;
      s += __shfl_xor(s, 1);
      s += __shfl_xor(s, 2);
      s += __shfl_xor(s, 4);
      s += __shfl_xor(s, 8);
      if (l15 == 0) wred[wave][quad * 4 + r] = s;
    }
  }
  __syncthreads();
  if (tid < 16) {
    float s = qb3[0];
#pragma unroll
    for (int w = 0; w < 16; w++) s += wred[w][tid];
    out[r0 + tid] = s;
  }
}

// ---------------------------------------------------------------------------
extern "C" void kernel_launch(void* const* d_in, const int* in_sizes, int n_in,
                              void* d_out, int out_size, void* d_ws, size_t ws_size,
                              hipStream_t stream) {
  const float* obs       = (const float*)d_in[0];
  const float* obstacles = (const float*)d_in[1];
  const float* act       = (const float*)d_in[2];
  const float* ow1       = (const float*)d_in[3];
  const float* ob1       = (const float*)d_in[4];
  const float* ow2       = (const float*)d_in[5];
  const float* ob2       = (const float*)d_in[6];
  const float* qw1       = (const float*)d_in[7];
  const float* qb1       = (const float*)d_in[8];
  const float* qw2       = (const float*)d_in[9];
  const float* qb2       = (const float*)d_in[10];
  const float* qw3       = (const float*)d_in[11];
  const float* qb3       = (const float*)d_in[12];
  float* out = (float*)d_out;

  unsigned short* ow1q = (unsigned short*)d_ws;   // 8192
  unsigned short* ow2p = ow1q + 8192;             // 65536
  unsigned short* qw1h = ow2p + 65536;            // 106496
  unsigned short* qw1l = qw1h + 106496;           // 106496
  unsigned short* qw2h = qw1l + 106496;           // 65536
  unsigned short* qw2l = qw2h + 65536;            // 65536
  unsigned short* poolH = qw2l + 65536;           // 4096*256
  unsigned short* poolL = poolH + 1048576;        // 4096*256

  pack_weights<<<416, 256, 0, stream>>>(ow1, ow2, qw1, qw2, ow1q, ow2p, qw1h,
                                        qw1l, qw2h, qw2l);
  obstacle_kernel<<<4096, 512, 0, stream>>>(obs, obstacles, ow1q, ow2p, ob1,
                                            ob2, poolH, poolL);
  head_mfma<<<256, 1024, 0, stream>>>(obs, act, poolH, poolL, qw1h, qw1l,
                                      qw2h, qw2l, qb1, qb2, qw3, qb3, out);
}